// Round 13
// baseline (119.413 us; speedup 1.0000x reference)
//
#include <hip/hip_runtime.h>
#include <math.h>

#define NE     50000
#define NNODE  10000
#define HDIM   128
#define GBIN   2048
#define NLUT   2049          // GBIN+1 rows
#define NC     4160          // 576 + 3584
#define NC1    576
#define NCHMAX 3611          // 2048 + ceil(50000/32)
#define MPAD   2064          // 129*16 padded grid rows

typedef _Float16 h2 __attribute__((ext_vector_type(2)));
typedef _Float16 h8 __attribute__((ext_vector_type(8)));
typedef float f32x4 __attribute__((ext_vector_type(4)));

// fp16 types for k_epi dot2 path
typedef __fp16 hp2 __attribute__((ext_vector_type(2)));
typedef __fp16 hp4 __attribute__((ext_vector_type(4)));
typedef __fp16 hp8 __attribute__((ext_vector_type(8)));

static __device__ __forceinline__ float fdot2f(hp2 p, hp2 q, float acc) {
  return __builtin_amdgcn_fdot2(p, q, acc, false);
}
static __device__ __forceinline__ hp2 pk2(float a, float b) {
  hp2 r = __builtin_amdgcn_cvt_pkrtz(a, b);
  return r;
}
static __device__ __forceinline__ hp2 mkh2(__fp16 a, __fp16 b) {
  hp2 o; o[0] = a; o[1] = b;
  return o;
}

// constants
#define SQ3C        1.7320508075688772f
#define INV_SQ3     0.5773502691896258f
#define C0_1F       0.20412414523193154f   // 1/sqrt(24)
#define C1_1_OS3F   0.20412414523193154f   // sqrt(3/24)/sqrt(3)
#define C0_2F       0.05590169943749474f   // 1/sqrt(320)
#define C1_2_OS3F   0.0625f                // sqrt(3/256)/sqrt(3)
#define INV_SQRT_H  0.08838834764831845f   // 1/sqrt(128)
#define DELTA       (5.0f/2048.0f)
#define INV_DELTA   409.6f
#define STEP_INV    (51.0f/5.0f)

// ---------------- K1a: H activations (fp16), actc/sqrt(H) folded ----------------
__global__ __launch_bounds__(128) void k_hprep(
    const float* __restrict__ lw1, const float* __restrict__ rw1,
    const float actc, const float K0C,
    _Float16* __restrict__ Hl, _Float16* __restrict__ Hr) {
  const int g  = blockIdx.x;
  const int which = blockIdx.y;
  const int hc = threadIdx.x;
  const float* __restrict__ w1 = which ? rw1 : lw1;
  float h = 0.f;
  if (g <= GBIN) {
    const float tt = (float)g * DELTA * STEP_INV;
    const int i0 = (int)floorf(tt);
    float z = 0.f;
#pragma unroll
    for (int k = 0; k < 2; ++k) {
      const int ii = i0 + k;
      if (ii >= 1 && ii <= 50) {
        const float diff = tt - (float)ii;
        const float a = diff + 1.f, b = 1.f - diff;
        if (a > 0.f && b > 0.f) {
          const float val = K0C * __expf(-1.f / a - 1.f / b);
          z += val * w1[(ii - 1) * HDIM + hc];
        }
      }
    }
    h = actc * z / (1.f + __expf(-z)) * INV_SQRT_H;
  }
  _Float16* __restrict__ H = which ? Hr : Hl;
  H[(size_t)g * HDIM + hc] = (_Float16)h;
}

// ---------------- K1b: W2 -> W2T[n][k] fp16 ----------------
__global__ __launch_bounds__(256) void k_w2t(
    const float* __restrict__ lw2, const float* __restrict__ rw2,
    _Float16* __restrict__ w2t) {
  const int gid = blockIdx.x * 256 + threadIdx.x;
  if (gid >= 64 * NC) return;
  const int k2 = gid / NC;
  const int n  = gid - k2 * NC;
  float a, b;
  if (n < NC1) {
    a = lw2[(size_t)(2 * k2) * NC1 + n];
    b = lw2[(size_t)(2 * k2 + 1) * NC1 + n];
  } else {
    const int m = n - NC1;
    a = rw2[(size_t)(2 * k2) * 3584 + m];
    b = rw2[(size_t)(2 * k2 + 1) * 3584 + m];
  }
  h2 p; p[0] = (_Float16)a; p[1] = (_Float16)b;
  *(h2*)(w2t + (size_t)n * HDIM + 2 * k2) = p;
}

// ---------------- K1c: LUT build via MFMA GEMM ----------------
__global__ __launch_bounds__(256) void k_lutm(
    const _Float16* __restrict__ Hl, const _Float16* __restrict__ Hr,
    const _Float16* __restrict__ w2t, _Float16* __restrict__ lut) {
  const int tid = threadIdx.x;
  const int nt = blockIdx.y * 4 + (tid >> 6);   // 0..259
  const int mt = blockIdx.x;                     // 0..128
  const int l  = tid & 63;
  const int rc = l & 15;
  const int kg = (l >> 4) * 8;
  const _Float16* __restrict__ Ap =
      ((nt < 36) ? Hl : Hr) + (size_t)(mt * 16 + rc) * HDIM + kg;
  const _Float16* __restrict__ Bp = w2t + (size_t)(nt * 16 + rc) * HDIM + kg;
  f32x4 acc = {0.f, 0.f, 0.f, 0.f};
#pragma unroll
  for (int kc = 0; kc < 4; ++kc) {
    h8 a = *(const h8*)(Ap + kc * 32);
    h8 b = *(const h8*)(Bp + kc * 32);
    acc = __builtin_amdgcn_mfma_f32_16x16x32_f16(a, b, acc, 0, 0, 0);
  }
#pragma unroll
  for (int r = 0; r < 4; ++r) {
    const int g = mt * 16 + (l >> 4) * 4 + r;
    if (g <= GBIN) lut[(size_t)g * NC + nt * 16 + rc] = (_Float16)acc[r];
  }
}

// ---------------- K2: per-edge bin/frac + histogram; zero inactive outputs ----------------
__global__ void k_edge(const int* __restrict__ ei, const float* __restrict__ pos,
                       float* __restrict__ out, int* __restrict__ bin_e,
                       float* __restrict__ f_e, int* __restrict__ cnt) {
  const int e = blockIdx.x * 256 + threadIdx.x;
  if (e >= NE) return;
  const int rec = ei[e], lig = ei[NE + e];
  const float ax = pos[lig * 3 + 0] - pos[rec * 3 + 0];
  const float ay = pos[lig * 3 + 1] - pos[rec * 3 + 1];
  const float az = pos[lig * 3 + 2] - pos[rec * 3 + 2];
  const float d = sqrtf(ax * ax + ay * ay + az * az);
  if (d > 0.f && d < 5.0f) {
    const float tf = d * INV_DELTA;
    int b = (int)tf;
    if (b > GBIN - 1) b = GBIN - 1;
    bin_e[e] = b;
    f_e[e] = tf - (float)b;
    atomicAdd(&cnt[b], 1);
  } else {
    bin_e[e] = -1;
    float* o = out + (size_t)e * 20;
#pragma unroll
    for (int i2 = 0; i2 < 20; ++i2) o[i2] = 0.f;
  }
}

// ---------------- K3a: scan + chunk-table emission (single block) ----------------
__global__ void k_scan(const int* __restrict__ cnt, int* __restrict__ offs,
                       int* __restrict__ woff, int* __restrict__ chunk_bin,
                       int* __restrict__ chunk_start, int* __restrict__ nch) {
  __shared__ int lds[256];
  const int t = threadIdx.x;
  int loc[8];
  int s = 0;
#pragma unroll
  for (int i = 0; i < 8; ++i) { loc[i] = cnt[t * 8 + i]; s += loc[i]; }
  lds[t] = s;
  __syncthreads();
  for (int o = 1; o < 256; o <<= 1) {
    int v = 0;
    if (t >= o) v = lds[t - o];
    __syncthreads();
    lds[t] += v;
    __syncthreads();
  }
  int run = lds[t] - s;
  int runs[8];
#pragma unroll
  for (int i = 0; i < 8; ++i) {
    runs[i] = run;
    offs[t * 8 + i] = run;
    woff[t * 8 + i] = run;
    run += loc[i];
  }
  if (t == 255) offs[GBIN] = run;

  int ccnt[8];
  int csum = 0;
#pragma unroll
  for (int i = 0; i < 8; ++i) { ccnt[i] = (loc[i] + 31) >> 5; csum += ccnt[i]; }
  __syncthreads();
  lds[t] = csum;
  __syncthreads();
  for (int o = 1; o < 256; o <<= 1) {
    int v = 0;
    if (t >= o) v = lds[t - o];
    __syncthreads();
    lds[t] += v;
    __syncthreads();
  }
  int crun = lds[t] - csum;
#pragma unroll
  for (int i = 0; i < 8; ++i) {
    for (int c = 0; c < ccnt[i]; ++c) {
      chunk_bin[crun]   = t * 8 + i;
      chunk_start[crun] = runs[i] + c * 32;
      ++crun;
    }
  }
  if (t == 255) nch[0] = lds[255];
}

// ---------------- K3b: counting-sort scatter ----------------
__global__ void k_scatter(const int* __restrict__ bin_e, int* __restrict__ woff,
                          int* __restrict__ sorted) {
  const int e = blockIdx.x * 256 + threadIdx.x;
  if (e >= NE) return;
  const int b = bin_e[e];
  if (b >= 0) {
    const int p = atomicAdd(&woff[b], 1);
    sorted[p] = e;
  }
}

// ---------------- K4: 32-edge chunk / 64 threads; quad j owns edges 2j, 2j+1 ----------
// Pair-interleaved fp16 LDS (16.6 KB); layer 1 per-edge (bounded registers);
// layer 2 merged sweep: each weight read feeds BOTH edges' fdot2 chains.

// layer-1 for one edge (fdot2 + lerp-in-dot): outputs allgathered SAF[16], VAF[24]
#define DO_L1(E, F, FM, SAF, VAF)                                              \
  {                                                                            \
    const int lig_ = ei[NE + (E)];                                             \
    const int rec_ = ei[(E)];                                                  \
    const float ax_ = pos[lig_ * 3 + 0] - pos[rec_ * 3 + 0];                   \
    const float ay_ = pos[lig_ * 3 + 1] - pos[rec_ * 3 + 1];                   \
    const float az_ = pos[lig_ * 3 + 2] - pos[rec_ * 3 + 2];                   \
    const float d_ = sqrtf(ax_ * ax_ + ay_ * ay_ + az_ * az_);                 \
    const float in_ = SQ3C / fmaxf(d_, 1e-12f);                                \
    const float sh0_ = ax_ * in_, sh1_ = ay_ * in_, sh2_ = az_ * in_;          \
    float s1_[16], v1_[24];                                                    \
    {                                                                          \
      const float4* xl_ = (const float4*)(x + (size_t)lig_ * 40);              \
      _Pragma("unroll")                                                        \
      for (int j = 0; j < 4; ++j) {                                            \
        float4 v = xl_[j];                                                     \
        s1_[j*4+0] = v.x; s1_[j*4+1] = v.y; s1_[j*4+2] = v.z; s1_[j*4+3] = v.w;\
      }                                                                        \
      _Pragma("unroll")                                                        \
      for (int j = 0; j < 6; ++j) {                                            \
        float4 v = xl_[4 + j];                                                 \
        v1_[j*4+0] = v.x; v1_[j*4+1] = v.y; v1_[j*4+2] = v.z; v1_[j*4+3] = v.w;\
      }                                                                        \
    }                                                                          \
    float vs_[8];                                                              \
    _Pragma("unroll")                                                          \
    for (int u = 0; u < 8; ++u)                                                \
      vs_[u] = (v1_[u*3]*sh0_ + v1_[u*3+1]*sh1_ + v1_[u*3+2]*sh2_) * INV_SQ3;  \
    float A_[4] = {0.f, 0.f, 0.f, 0.f};                                        \
    _Pragma("unroll")                                                          \
    for (int u = 0; u < 16; ++u) {                                             \
      hp8 w = *(const hp8*)(WP + 2 * (u * 16 + s * 4));                        \
      hp2 sp = pk2(s1_[u] * (FM), s1_[u] * (F));                               \
      A_[0] = fdot2f(mkh2(w[0], w[1]), sp, A_[0]);                             \
      A_[1] = fdot2f(mkh2(w[2], w[3]), sp, A_[1]);                             \
      A_[2] = fdot2f(mkh2(w[4], w[5]), sp, A_[2]);                             \
      A_[3] = fdot2f(mkh2(w[6], w[7]), sp, A_[3]);                             \
    }                                                                          \
    _Pragma("unroll")                                                          \
    for (int u = 0; u < 8; ++u) {                                              \
      hp8 w = *(const hp8*)(WP + 2 * (448 + u * 16 + s * 4));                  \
      hp2 sp = pk2(vs_[u] * (FM), vs_[u] * (F));                               \
      A_[0] = fdot2f(mkh2(w[0], w[1]), sp, A_[0]);                             \
      A_[1] = fdot2f(mkh2(w[2], w[3]), sp, A_[1]);                             \
      A_[2] = fdot2f(mkh2(w[4], w[5]), sp, A_[2]);                             \
      A_[3] = fdot2f(mkh2(w[6], w[7]), sp, A_[3]);                             \
    }                                                                          \
    const float sa0_ = C0_1F * A_[0];                                          \
    const float sa1_ = C0_1F * A_[1];                                          \
    const float sa2_ = C0_1F * A_[2];                                          \
    const float sa3_ = C0_1F * A_[3];                                          \
    float cA_ = 0.f, cB_ = 0.f;                                                \
    _Pragma("unroll")                                                          \
    for (int u = 0; u < 16; ++u) {                                             \
      hp4 w = *(const hp4*)(WP + 2 * (256 + u * 8 + s * 2));                   \
      hp2 sp = pk2(s1_[u] * (FM), s1_[u] * (F));                               \
      cA_ = fdot2f(mkh2(w[0], w[1]), sp, cA_);                                 \
      cB_ = fdot2f(mkh2(w[2], w[3]), sp, cB_);                                 \
    }                                                                          \
    float tAx_=0.f, tAy_=0.f, tAz_=0.f, tBx_=0.f, tBy_=0.f, tBz_=0.f;          \
    _Pragma("unroll")                                                          \
    for (int u = 0; u < 8; ++u) {                                              \
      hp4 w = *(const hp4*)(WP + 2 * (384 + u * 8 + s * 2));                   \
      hp2 px = pk2(v1_[u*3] * (FM),     v1_[u*3] * (F));                       \
      hp2 py = pk2(v1_[u*3+1] * (FM),   v1_[u*3+1] * (F));                     \
      hp2 pz = pk2(v1_[u*3+2] * (FM),   v1_[u*3+2] * (F));                     \
      hp2 pa = mkh2(w[0], w[1]);                                               \
      hp2 pb = mkh2(w[2], w[3]);                                               \
      tAx_ = fdot2f(pa, px, tAx_); tAy_ = fdot2f(pa, py, tAy_);                \
      tAz_ = fdot2f(pa, pz, tAz_);                                             \
      tBx_ = fdot2f(pb, px, tBx_); tBy_ = fdot2f(pb, py, tBy_);                \
      tBz_ = fdot2f(pb, pz, tBz_);                                             \
    }                                                                          \
    const float vaA0_ = C1_1_OS3F * (cA_ * sh0_ + tAx_);                       \
    const float vaA1_ = C1_1_OS3F * (cA_ * sh1_ + tAy_);                       \
    const float vaA2_ = C1_1_OS3F * (cA_ * sh2_ + tAz_);                       \
    const float vaB0_ = C1_1_OS3F * (cB_ * sh0_ + tBx_);                       \
    const float vaB1_ = C1_1_OS3F * (cB_ * sh1_ + tBy_);                       \
    const float vaB2_ = C1_1_OS3F * (cB_ * sh2_ + tBz_);                       \
    _Pragma("unroll")                                                          \
    for (int k = 0; k < 16; ++k) {                                             \
      const float v = ((k&3)==0) ? sa0_ : ((k&3)==1) ? sa1_ :                  \
                      ((k&3)==2) ? sa2_ : sa3_;                                \
      SAF[k] = __shfl(v, qb + (k >> 2), 64);                                   \
    }                                                                          \
    _Pragma("unroll")                                                          \
    for (int w = 0; w < 8; ++w) {                                              \
      const int src = qb + (w >> 1);                                           \
      const float x0 = (w & 1) ? vaB0_ : vaA0_;                                \
      const float x1 = (w & 1) ? vaB1_ : vaA1_;                                \
      const float x2 = (w & 1) ? vaB2_ : vaA2_;                                \
      VAF[w*3+0] = __shfl(x0, src, 64);                                        \
      VAF[w*3+1] = __shfl(x1, src, 64);                                        \
      VAF[w*3+2] = __shfl(x2, src, 64);                                        \
    }                                                                          \
  }

__global__ __launch_bounds__(64) void k_epi(
    const _Float16* __restrict__ lut, const int* __restrict__ chunk_bin,
    const int* __restrict__ chunk_start, const int* __restrict__ offs,
    const int* __restrict__ sorted, const float* __restrict__ f_e,
    const int* __restrict__ ei, const float* __restrict__ pos,
    const float* __restrict__ x, float* __restrict__ out,
    const int* __restrict__ nch) {
  __shared__ __fp16 WP[2 * NC];        // 16640 B
  const int bid = blockIdx.x;
  if (bid >= nch[0]) return;
  const int b     = chunk_bin[bid];
  const int start = chunk_start[bid];
  const int end0  = offs[b + 1];
  const int end   = (start + 32 < end0) ? (start + 32) : end0;
  const int tid = threadIdx.x;
  {  // stage: interleave rows b, b+1 into pairs
    const hp8* r0 = (const hp8*)(lut + (size_t)b * NC);
    const hp8* r1 = (const hp8*)(lut + (size_t)(b + 1) * NC);
    hp8* dst = (hp8*)WP;
    for (int i = tid; i < NC / 8; i += 64) {
      hp8 a = r0[i], c = r1[i];
      dst[2 * i]     = __builtin_shufflevector(a, c, 0, 8, 1, 9, 2, 10, 3, 11);
      dst[2 * i + 1] = __builtin_shufflevector(a, c, 4, 12, 5, 13, 6, 14, 7, 15);
    }
  }
  __syncthreads();
  const int s  = tid & 3;
  const int qb = tid & ~3;
  const int slotA = start + 2 * (tid >> 2);
  if (slotA >= end) return;
  const int slotB = slotA + 1;
  const int validB = (slotB < end);

  const int eA = sorted[slotA];
  const int eB = sorted[validB ? slotB : slotA];
  const float fA = f_e[eA], fmA = 1.f - fA;
  const float fB = f_e[eB], fmB = 1.f - fB;

  // ---- layer 1 per edge (sequential: only one edge's features live at a time) ----
  float saFA[16], vaFA[24], saFB[16], vaFB[24];
  DO_L1(eA, fA, fmA, saFA, vaFA);
  DO_L1(eB, fB, fmB, saFB, vaFB);

  // ---- rec features: lane's v-subset per edge ----
  float sblA[4], vbA[6], sblB[4], vbB[6];
  {
    const float* xr = x + (size_t)ei[eA] * 40;
#pragma unroll
    for (int j = 0; j < 4; ++j) sblA[j] = xr[j * 4 + s];
#pragma unroll
    for (int k = 0; k < 3; ++k) {
      vbA[k]     = xr[16 + s * 3 + k];
      vbA[3 + k] = xr[16 + (s + 4) * 3 + k];
    }
    const float* xr2 = x + (size_t)ei[eB] * 40;
#pragma unroll
    for (int j = 0; j < 4; ++j) sblB[j] = xr2[j * 4 + s];
#pragma unroll
    for (int k = 0; k < 3; ++k) {
      vbB[k]     = xr2[16 + s * 3 + k];
      vbB[3 + k] = xr2[16 + (s + 4) * 3 + k];
    }
  }

  float oeA[20], oeB[20];

  // ===== layer 2: s_out, merged sweep (shared weight reads) =====
  {
    float soA[8], soB[8];
#pragma unroll
    for (int w = 0; w < 8; ++w) { soA[w] = 0.f; soB[w] = 0.f; }
    // W000 @ 576: [u:16][v:16][w:8], v = vv*4+s
#pragma unroll
    for (int u = 0; u < 16; ++u) {
      const float suA = saFA[u], suB = saFB[u];
      const __fp16* rp = WP + 2 * (576 + u * 128 + s * 8);
#pragma unroll
      for (int vv = 0; vv < 4; ++vv) {
        const float qA = suA * sblA[vv];
        const float qB = suB * sblB[vv];
        hp2 qpA = pk2(qA * fmA, qA * fA);
        hp2 qpB = pk2(qB * fmB, qB * fB);
        hp8 wa = *(const hp8*)(rp + 2 * (vv * 32));
        hp8 wb = *(const hp8*)(rp + 2 * (vv * 32) + 8);
        hp2 p0 = mkh2(wa[0], wa[1]), p1 = mkh2(wa[2], wa[3]);
        hp2 p2 = mkh2(wa[4], wa[5]), p3 = mkh2(wa[6], wa[7]);
        hp2 p4 = mkh2(wb[0], wb[1]), p5 = mkh2(wb[2], wb[3]);
        hp2 p6 = mkh2(wb[4], wb[5]), p7 = mkh2(wb[6], wb[7]);
        soA[0] = fdot2f(p0, qpA, soA[0]); soA[1] = fdot2f(p1, qpA, soA[1]);
        soA[2] = fdot2f(p2, qpA, soA[2]); soA[3] = fdot2f(p3, qpA, soA[3]);
        soA[4] = fdot2f(p4, qpA, soA[4]); soA[5] = fdot2f(p5, qpA, soA[5]);
        soA[6] = fdot2f(p6, qpA, soA[6]); soA[7] = fdot2f(p7, qpA, soA[7]);
        soB[0] = fdot2f(p0, qpB, soB[0]); soB[1] = fdot2f(p1, qpB, soB[1]);
        soB[2] = fdot2f(p2, qpB, soB[2]); soB[3] = fdot2f(p3, qpB, soB[3]);
        soB[4] = fdot2f(p4, qpB, soB[4]); soB[5] = fdot2f(p5, qpB, soB[5]);
        soB[6] = fdot2f(p6, qpB, soB[6]); soB[7] = fdot2f(p7, qpB, soB[7]);
      }
    }
    // W110 @ 3648: [u:8][v:8][w:8], v = vv*4+s
#pragma unroll
    for (int u = 0; u < 8; ++u) {
      const float aA0 = vaFA[u*3], aA1 = vaFA[u*3+1], aA2 = vaFA[u*3+2];
      const float aB0 = vaFB[u*3], aB1 = vaFB[u*3+1], aB2 = vaFB[u*3+2];
      const __fp16* rp = WP + 2 * (3648 + u * 64 + s * 8);
#pragma unroll
      for (int vv = 0; vv < 2; ++vv) {
        const float dA = (aA0*vbA[vv*3] + aA1*vbA[vv*3+1] + aA2*vbA[vv*3+2]) * INV_SQ3;
        const float dB = (aB0*vbB[vv*3] + aB1*vbB[vv*3+1] + aB2*vbB[vv*3+2]) * INV_SQ3;
        hp2 qpA = pk2(dA * fmA, dA * fA);
        hp2 qpB = pk2(dB * fmB, dB * fB);
        hp8 wa = *(const hp8*)(rp + 2 * (vv * 32));
        hp8 wb = *(const hp8*)(rp + 2 * (vv * 32) + 8);
        hp2 p0 = mkh2(wa[0], wa[1]), p1 = mkh2(wa[2], wa[3]);
        hp2 p2 = mkh2(wa[4], wa[5]), p3 = mkh2(wa[6], wa[7]);
        hp2 p4 = mkh2(wb[0], wb[1]), p5 = mkh2(wb[2], wb[3]);
        hp2 p6 = mkh2(wb[4], wb[5]), p7 = mkh2(wb[6], wb[7]);
        soA[0] = fdot2f(p0, qpA, soA[0]); soA[1] = fdot2f(p1, qpA, soA[1]);
        soA[2] = fdot2f(p2, qpA, soA[2]); soA[3] = fdot2f(p3, qpA, soA[3]);
        soA[4] = fdot2f(p4, qpA, soA[4]); soA[5] = fdot2f(p5, qpA, soA[5]);
        soA[6] = fdot2f(p6, qpA, soA[6]); soA[7] = fdot2f(p7, qpA, soA[7]);
        soB[0] = fdot2f(p0, qpB, soB[0]); soB[1] = fdot2f(p1, qpB, soB[1]);
        soB[2] = fdot2f(p2, qpB, soB[2]); soB[3] = fdot2f(p3, qpB, soB[3]);
        soB[4] = fdot2f(p4, qpB, soB[4]); soB[5] = fdot2f(p5, qpB, soB[5]);
        soB[6] = fdot2f(p6, qpB, soB[6]); soB[7] = fdot2f(p7, qpB, soB[7]);
      }
    }
#pragma unroll
    for (int w = 0; w < 8; ++w) {
      oeA[w] = C0_2F * soA[w];
      oeB[w] = C0_2F * soB[w];
    }
  }

  // ===== layer 2: v_out, merged sweep =====
  {
    float uoA[12], uoB[12];
#pragma unroll
    for (int w = 0; w < 12; ++w) { uoA[w] = 0.f; uoB[w] = 0.f; }
    // W011 @ 2624: [u:16][v:8][w:4], v = vv*4+s
#pragma unroll
    for (int u = 0; u < 16; ++u) {
      const float suA = saFA[u], suB = saFB[u];
      const __fp16* rp = WP + 2 * (2624 + u * 32 + s * 4);
#pragma unroll
      for (int vv = 0; vv < 2; ++vv) {
        const float qA0 = suA * vbA[vv*3], qA1 = suA * vbA[vv*3+1], qA2 = suA * vbA[vv*3+2];
        const float qB0 = suB * vbB[vv*3], qB1 = suB * vbB[vv*3+1], qB2 = suB * vbB[vv*3+2];
        hp2 qA0p = pk2(qA0 * fmA, qA0 * fA);
        hp2 qA1p = pk2(qA1 * fmA, qA1 * fA);
        hp2 qA2p = pk2(qA2 * fmA, qA2 * fA);
        hp2 qB0p = pk2(qB0 * fmB, qB0 * fB);
        hp2 qB1p = pk2(qB1 * fmB, qB1 * fB);
        hp2 qB2p = pk2(qB2 * fmB, qB2 * fB);
        hp8 w = *(const hp8*)(rp + 2 * (vv * 16));
        hp2 p0 = mkh2(w[0], w[1]);
        hp2 p1 = mkh2(w[2], w[3]);
        hp2 p2 = mkh2(w[4], w[5]);
        hp2 p3 = mkh2(w[6], w[7]);
        uoA[0] = fdot2f(p0, qA0p, uoA[0]); uoA[1]  = fdot2f(p0, qA1p, uoA[1]);  uoA[2]  = fdot2f(p0, qA2p, uoA[2]);
        uoA[3] = fdot2f(p1, qA0p, uoA[3]); uoA[4]  = fdot2f(p1, qA1p, uoA[4]);  uoA[5]  = fdot2f(p1, qA2p, uoA[5]);
        uoA[6] = fdot2f(p2, qA0p, uoA[6]); uoA[7]  = fdot2f(p2, qA1p, uoA[7]);  uoA[8]  = fdot2f(p2, qA2p, uoA[8]);
        uoA[9] = fdot2f(p3, qA0p, uoA[9]); uoA[10] = fdot2f(p3, qA1p, uoA[10]); uoA[11] = fdot2f(p3, qA2p, uoA[11]);
        uoB[0] = fdot2f(p0, qB0p, uoB[0]); uoB[1]  = fdot2f(p0, qB1p, uoB[1]);  uoB[2]  = fdot2f(p0, qB2p, uoB[2]);
        uoB[3] = fdot2f(p1, qB0p, uoB[3]); uoB[4]  = fdot2f(p1, qB1p, uoB[4]);  uoB[5]  = fdot2f(p1, qB2p, uoB[5]);
        uoB[6] = fdot2f(p2, qB0p, uoB[6]); uoB[7]  = fdot2f(p2, qB1p, uoB[7]);  uoB[8]  = fdot2f(p2, qB2p, uoB[8]);
        uoB[9] = fdot2f(p3, qB0p, uoB[9]); uoB[10] = fdot2f(p3, qB1p, uoB[10]); uoB[11] = fdot2f(p3, qB2p, uoB[11]);
      }
    }
    // W101 @ 3136: [u:8][v:16][w:4], v = vv*4+s
#pragma unroll
    for (int u = 0; u < 8; ++u) {
      const float aA0 = vaFA[u*3], aA1 = vaFA[u*3+1], aA2 = vaFA[u*3+2];
      const float aB0 = vaFB[u*3], aB1 = vaFB[u*3+1], aB2 = vaFB[u*3+2];
      const __fp16* rp = WP + 2 * (3136 + u * 64 + s * 4);
#pragma unroll
      for (int vv = 0; vv < 4; ++vv) {
        const float sA = sblA[vv], sB = sblB[vv];
        const float qA0 = aA0 * sA, qA1 = aA1 * sA, qA2 = aA2 * sA;
        const float qB0 = aB0 * sB, qB1 = aB1 * sB, qB2 = aB2 * sB;
        hp2 qA0p = pk2(qA0 * fmA, qA0 * fA);
        hp2 qA1p = pk2(qA1 * fmA, qA1 * fA);
        hp2 qA2p = pk2(qA2 * fmA, qA2 * fA);
        hp2 qB0p = pk2(qB0 * fmB, qB0 * fB);
        hp2 qB1p = pk2(qB1 * fmB, qB1 * fB);
        hp2 qB2p = pk2(qB2 * fmB, qB2 * fB);
        hp8 w = *(const hp8*)(rp + 2 * (vv * 16));
        hp2 p0 = mkh2(w[0], w[1]);
        hp2 p1 = mkh2(w[2], w[3]);
        hp2 p2 = mkh2(w[4], w[5]);
        hp2 p3 = mkh2(w[6], w[7]);
        uoA[0] = fdot2f(p0, qA0p, uoA[0]); uoA[1]  = fdot2f(p0, qA1p, uoA[1]);  uoA[2]  = fdot2f(p0, qA2p, uoA[2]);
        uoA[3] = fdot2f(p1, qA0p, uoA[3]); uoA[4]  = fdot2f(p1, qA1p, uoA[4]);  uoA[5]  = fdot2f(p1, qA2p, uoA[5]);
        uoA[6] = fdot2f(p2, qA0p, uoA[6]); uoA[7]  = fdot2f(p2, qA1p, uoA[7]);  uoA[8]  = fdot2f(p2, qA2p, uoA[8]);
        uoA[9] = fdot2f(p3, qA0p, uoA[9]); uoA[10] = fdot2f(p3, qA1p, uoA[10]); uoA[11] = fdot2f(p3, qA2p, uoA[11]);
        uoB[0] = fdot2f(p0, qB0p, uoB[0]); uoB[1]  = fdot2f(p0, qB1p, uoB[1]);  uoB[2]  = fdot2f(p0, qB2p, uoB[2]);
        uoB[3] = fdot2f(p1, qB0p, uoB[3]); uoB[4]  = fdot2f(p1, qB1p, uoB[4]);  uoB[5]  = fdot2f(p1, qB2p, uoB[5]);
        uoB[6] = fdot2f(p2, qB0p, uoB[6]); uoB[7]  = fdot2f(p2, qB1p, uoB[7]);  uoB[8]  = fdot2f(p2, qB2p, uoB[8]);
        uoB[9] = fdot2f(p3, qB0p, uoB[9]); uoB[10] = fdot2f(p3, qB1p, uoB[10]); uoB[11] = fdot2f(p3, qB2p, uoB[11]);
      }
    }
#pragma unroll
    for (int w = 0; w < 12; ++w) {
      oeA[8 + w] = C1_2_OS3F * uoA[w];
      oeB[8 + w] = C1_2_OS3F * uoB[w];
    }
  }

  // ---- quad butterfly reduce + store ----
#pragma unroll
  for (int w = 0; w < 20; ++w) {
    oeA[w] += __shfl_xor(oeA[w], 1, 64);
    oeA[w] += __shfl_xor(oeA[w], 2, 64);
    oeB[w] += __shfl_xor(oeB[w], 1, 64);
    oeB[w] += __shfl_xor(oeB[w], 2, 64);
  }
  if (s == 0) {
    float4* opA = (float4*)(out + (size_t)eA * 20);
#pragma unroll
    for (int j = 0; j < 5; ++j) {
      float4 o4;
      o4.x = oeA[j*4+0]; o4.y = oeA[j*4+1]; o4.z = oeA[j*4+2]; o4.w = oeA[j*4+3];
      opA[j] = o4;
    }
    if (validB) {
      float4* opB = (float4*)(out + (size_t)eB * 20);
#pragma unroll
      for (int j = 0; j < 5; ++j) {
        float4 o4;
        o4.x = oeB[j*4+0]; o4.y = oeB[j*4+1]; o4.z = oeB[j*4+2]; o4.w = oeB[j*4+3];
        opB[j] = o4;
      }
    }
  }
}

// ---------------- host ----------------
extern "C" void kernel_launch(void* const* d_in, const int* in_sizes, int n_in,
                              void* d_out, int out_size, void* d_ws, size_t ws_size,
                              hipStream_t stream) {
  const int*   ei  = (const int*)d_in[0];
  const float* pos = (const float*)d_in[1];
  const float* x   = (const float*)d_in[2];
  const float* lw1 = (const float*)d_in[3];
  const float* lw2 = (const float*)d_in[4];
  const float* rw1 = (const float*)d_in[5];
  const float* rw2 = (const float*)d_in[6];
  float* out = (float*)d_out;
  char*  ws  = (char*)d_ws;

  size_t o = 0;
  _Float16* lut = (_Float16*)(ws + o); o += (size_t)NLUT * NC * 2;
  o = (o + 15) & ~(size_t)15;
  _Float16* Hl  = (_Float16*)(ws + o); o += (size_t)MPAD * HDIM * 2;
  _Float16* Hr  = (_Float16*)(ws + o); o += (size_t)MPAD * HDIM * 2;
  _Float16* w2t = (_Float16*)(ws + o); o += (size_t)NC * HDIM * 2;
  o = (o + 15) & ~(size_t)15;
  int*   bin_e = (int*)(ws + o);  o += (size_t)NE * 4;
  float* f_e   = (float*)(ws + o); o += (size_t)NE * 4;
  int*   cnt   = (int*)(ws + o);  o += (size_t)GBIN * 4;
  int*   offs  = (int*)(ws + o);  o += (size_t)(GBIN + 1) * 4 + 12;
  int*   woff  = (int*)(ws + o);  o += (size_t)GBIN * 4;
  int*   sorted = (int*)(ws + o); o += (size_t)NE * 4;
  int*   chunk_bin   = (int*)(ws + o); o += (size_t)NCHMAX * 4;
  int*   chunk_start = (int*)(ws + o); o += (size_t)NCHMAX * 4;
  int*   nch = (int*)(ws + o); o += 16;

  // ACT_C on host (runs at capture time, not in the timed graph)
  double ssum = 0.0;
  const double dz = 20.0 / 40000.0;
  for (int i = 0; i <= 40000; ++i) {
    const double z = -10.0 + dz * (double)i;
    const double sil = z / (1.0 + exp(-z));
    const double phi = exp(-0.5 * z * z) / sqrt(2.0 * M_PI);
    ssum += sil * sil * phi;
  }
  const float actc = (float)(1.0 / sqrt(ssum * dz));
  const float k0c  = (float)(1.14136 * exp(2.0));

  hipMemsetAsync(cnt, 0, GBIN * 4, stream);
  k_hprep<<<dim3(MPAD, 2), 128, 0, stream>>>(lw1, rw1, actc, k0c, Hl, Hr);
  k_w2t<<<(64 * NC + 255) / 256, 256, 0, stream>>>(lw2, rw2, w2t);
  k_lutm<<<dim3(129, 65), 256, 0, stream>>>(Hl, Hr, w2t, lut);
  k_edge<<<(NE + 255) / 256, 256, 0, stream>>>(ei, pos, out, bin_e, f_e, cnt);
  k_scan<<<1, 256, 0, stream>>>(cnt, offs, woff, chunk_bin, chunk_start, nch);
  k_scatter<<<(NE + 255) / 256, 256, 0, stream>>>(bin_e, woff, sorted);
  k_epi<<<NCHMAX, 64, 0, stream>>>(lut, chunk_bin, chunk_start, offs, sorted, f_e,
                                   ei, pos, x, out, nch);
}

// Round 14
// 107.046 us; speedup vs baseline: 1.1155x; 1.1155x over previous
//
#include <hip/hip_runtime.h>
#include <math.h>

#define NE     50000
#define NNODE  10000
#define HDIM   128
#define GBIN   2048
#define NLUT   2049          // GBIN+1 rows
#define NC     4160          // 576 + 3584
#define NC1    576
#define NCHMAX 3611          // 2048 + ceil(50000/32)
#define MPAD   2064          // 129*16 padded grid rows
#define NB_W2T 1040          // (64*NC)/256
#define NB_EDGE 196          // ceil(NE/256)

typedef _Float16 h2 __attribute__((ext_vector_type(2)));
typedef _Float16 h8 __attribute__((ext_vector_type(8)));
typedef float f32x4 __attribute__((ext_vector_type(4)));

// fp16 types for k_epi dot2 path
typedef __fp16 hp2 __attribute__((ext_vector_type(2)));
typedef __fp16 hp4 __attribute__((ext_vector_type(4)));
typedef __fp16 hp8 __attribute__((ext_vector_type(8)));

static __device__ __forceinline__ float fdot2f(hp2 p, hp2 q, float acc) {
  return __builtin_amdgcn_fdot2(p, q, acc, false);
}
static __device__ __forceinline__ hp2 pk2(float a, float b) {
  hp2 r = __builtin_amdgcn_cvt_pkrtz(a, b);
  return r;
}
static __device__ __forceinline__ hp2 mkh2(__fp16 a, __fp16 b) {
  hp2 o; o[0] = a; o[1] = b;
  return o;
}

// constants
#define SQ3C        1.7320508075688772f
#define INV_SQ3     0.5773502691896258f
#define C0_1F       0.20412414523193154f   // 1/sqrt(24)
#define C1_1_OS3F   0.20412414523193154f   // sqrt(3/24)/sqrt(3)
#define C0_2F       0.05590169943749474f   // 1/sqrt(320)
#define C1_2_OS3F   0.0625f                // sqrt(3/256)/sqrt(3)
#define INV_SQRT_H  0.08838834764831845f   // 1/sqrt(128)
#define DELTA       (5.0f/2048.0f)
#define INV_DELTA   409.6f
#define STEP_INV    (51.0f/5.0f)

// ---------------- K1: fused prologue ----------------
// blocks [0, MPAD)                : H activations (fp16), both MLPs (which = tid>>7)
// blocks [MPAD, MPAD+NB_W2T)      : W2 -> W2T[n][k] fp16
// blocks [MPAD+NB_W2T, +NB_EDGE)  : per-edge bin/frac + histogram + zero inactive
__global__ __launch_bounds__(256) void k_fused(
    const float* __restrict__ lw1, const float* __restrict__ rw1,
    const float* __restrict__ lw2, const float* __restrict__ rw2,
    const float actc, const float K0C,
    _Float16* __restrict__ Hl, _Float16* __restrict__ Hr,
    _Float16* __restrict__ w2t,
    const int* __restrict__ ei, const float* __restrict__ pos,
    float* __restrict__ out, int* __restrict__ bin_e,
    float* __restrict__ f_e, int* __restrict__ cnt) {
  const int bid = blockIdx.x;
  const int tid = threadIdx.x;
  if (bid < MPAD) {
    // ---- H prep ----
    const int g = bid;
    const int which = tid >> 7, hc = tid & 127;
    const float* __restrict__ w1 = which ? rw1 : lw1;
    float h = 0.f;
    if (g <= GBIN) {
      const float tt = (float)g * DELTA * STEP_INV;
      const int i0 = (int)floorf(tt);
      float z = 0.f;
#pragma unroll
      for (int k = 0; k < 2; ++k) {
        const int ii = i0 + k;
        if (ii >= 1 && ii <= 50) {
          const float diff = tt - (float)ii;
          const float a = diff + 1.f, b = 1.f - diff;
          if (a > 0.f && b > 0.f) {
            const float val = K0C * __expf(-1.f / a - 1.f / b);
            z += val * w1[(ii - 1) * HDIM + hc];
          }
        }
      }
      h = actc * z / (1.f + __expf(-z)) * INV_SQRT_H;
    }
    _Float16* __restrict__ H = which ? Hr : Hl;
    H[(size_t)g * HDIM + hc] = (_Float16)h;
  } else if (bid < MPAD + NB_W2T) {
    // ---- W2 transpose ----
    const int gid = (bid - MPAD) * 256 + tid;
    const int k2 = gid / NC;
    const int n  = gid - k2 * NC;
    float a, b;
    if (n < NC1) {
      a = lw2[(size_t)(2 * k2) * NC1 + n];
      b = lw2[(size_t)(2 * k2 + 1) * NC1 + n];
    } else {
      const int m = n - NC1;
      a = rw2[(size_t)(2 * k2) * 3584 + m];
      b = rw2[(size_t)(2 * k2 + 1) * 3584 + m];
    }
    h2 p; p[0] = (_Float16)a; p[1] = (_Float16)b;
    *(h2*)(w2t + (size_t)n * HDIM + 2 * k2) = p;
  } else {
    // ---- edge binning ----
    const int e = (bid - MPAD - NB_W2T) * 256 + tid;
    if (e >= NE) return;
    const int rec = ei[e], lig = ei[NE + e];
    const float ax = pos[lig * 3 + 0] - pos[rec * 3 + 0];
    const float ay = pos[lig * 3 + 1] - pos[rec * 3 + 1];
    const float az = pos[lig * 3 + 2] - pos[rec * 3 + 2];
    const float d = sqrtf(ax * ax + ay * ay + az * az);
    if (d > 0.f && d < 5.0f) {
      const float tf = d * INV_DELTA;
      int b = (int)tf;
      if (b > GBIN - 1) b = GBIN - 1;
      bin_e[e] = b;
      f_e[e] = tf - (float)b;
      atomicAdd(&cnt[b], 1);
    } else {
      bin_e[e] = -1;
      float* o = out + (size_t)e * 20;
#pragma unroll
      for (int i2 = 0; i2 < 20; ++i2) o[i2] = 0.f;
    }
  }
}

// ---------------- K1c: LUT build via MFMA GEMM ----------------
__global__ __launch_bounds__(256) void k_lutm(
    const _Float16* __restrict__ Hl, const _Float16* __restrict__ Hr,
    const _Float16* __restrict__ w2t, _Float16* __restrict__ lut) {
  const int tid = threadIdx.x;
  const int nt = blockIdx.y * 4 + (tid >> 6);   // 0..259
  const int mt = blockIdx.x;                     // 0..128
  const int l  = tid & 63;
  const int rc = l & 15;
  const int kg = (l >> 4) * 8;
  const _Float16* __restrict__ Ap =
      ((nt < 36) ? Hl : Hr) + (size_t)(mt * 16 + rc) * HDIM + kg;
  const _Float16* __restrict__ Bp = w2t + (size_t)(nt * 16 + rc) * HDIM + kg;
  f32x4 acc = {0.f, 0.f, 0.f, 0.f};
#pragma unroll
  for (int kc = 0; kc < 4; ++kc) {
    h8 a = *(const h8*)(Ap + kc * 32);
    h8 b = *(const h8*)(Bp + kc * 32);
    acc = __builtin_amdgcn_mfma_f32_16x16x32_f16(a, b, acc, 0, 0, 0);
  }
#pragma unroll
  for (int r = 0; r < 4; ++r) {
    const int g = mt * 16 + (l >> 4) * 4 + r;
    if (g <= GBIN) lut[(size_t)g * NC + nt * 16 + rc] = (_Float16)acc[r];
  }
}

// ---------------- K3a: scan + chunk-table emission (single block) ----------------
__global__ void k_scan(const int* __restrict__ cnt, int* __restrict__ offs,
                       int* __restrict__ woff, int* __restrict__ chunk_bin,
                       int* __restrict__ chunk_start, int* __restrict__ nch) {
  __shared__ int lds[256];
  const int t = threadIdx.x;
  int loc[8];
  int s = 0;
#pragma unroll
  for (int i = 0; i < 8; ++i) { loc[i] = cnt[t * 8 + i]; s += loc[i]; }
  lds[t] = s;
  __syncthreads();
  for (int o = 1; o < 256; o <<= 1) {
    int v = 0;
    if (t >= o) v = lds[t - o];
    __syncthreads();
    lds[t] += v;
    __syncthreads();
  }
  int run = lds[t] - s;
  int runs[8];
#pragma unroll
  for (int i = 0; i < 8; ++i) {
    runs[i] = run;
    offs[t * 8 + i] = run;
    woff[t * 8 + i] = run;
    run += loc[i];
  }
  if (t == 255) offs[GBIN] = run;

  int ccnt[8];
  int csum = 0;
#pragma unroll
  for (int i = 0; i < 8; ++i) { ccnt[i] = (loc[i] + 31) >> 5; csum += ccnt[i]; }
  __syncthreads();
  lds[t] = csum;
  __syncthreads();
  for (int o = 1; o < 256; o <<= 1) {
    int v = 0;
    if (t >= o) v = lds[t - o];
    __syncthreads();
    lds[t] += v;
    __syncthreads();
  }
  int crun = lds[t] - csum;
#pragma unroll
  for (int i = 0; i < 8; ++i) {
    for (int c = 0; c < ccnt[i]; ++c) {
      chunk_bin[crun]   = t * 8 + i;
      chunk_start[crun] = runs[i] + c * 32;
      ++crun;
    }
  }
  if (t == 255) nch[0] = lds[255];
}

// ---------------- K3b: counting-sort scatter ----------------
__global__ void k_scatter(const int* __restrict__ bin_e, int* __restrict__ woff,
                          int* __restrict__ sorted) {
  const int e = blockIdx.x * 256 + threadIdx.x;
  if (e >= NE) return;
  const int b = bin_e[e];
  if (b >= 0) {
    const int p = atomicAdd(&woff[b], 1);
    sorted[p] = e;
  }
}

// ---------------- K4: epilogue: 32-edge chunk / 128 threads; pair-interleaved fp16 LDS ----
// (R12 proven config: 41.4 us, VGPR 52.) LDS pair n = (W0[n], W1[n]) at WP[2n];
// lerp folded into fdot2(pair, (q*(1-f), q*f)); fp32 accumulate.
__global__ __launch_bounds__(128) void k_epi(
    const _Float16* __restrict__ lut, const int* __restrict__ chunk_bin,
    const int* __restrict__ chunk_start, const int* __restrict__ offs,
    const int* __restrict__ sorted, const float* __restrict__ f_e,
    const int* __restrict__ ei, const float* __restrict__ pos,
    const float* __restrict__ x, float* __restrict__ out,
    const int* __restrict__ nch) {
  __shared__ __fp16 WP[2 * NC];        // 16640 B
  const int bid = blockIdx.x;
  if (bid >= nch[0]) return;
  const int b     = chunk_bin[bid];
  const int start = chunk_start[bid];
  const int end0  = offs[b + 1];
  const int end   = (start + 32 < end0) ? (start + 32) : end0;
  const int tid = threadIdx.x;
  {  // stage: interleave rows b, b+1 into pairs
    const hp8* r0 = (const hp8*)(lut + (size_t)b * NC);
    const hp8* r1 = (const hp8*)(lut + (size_t)(b + 1) * NC);
    hp8* dst = (hp8*)WP;
    for (int i = tid; i < NC / 8; i += 128) {
      hp8 a = r0[i], c = r1[i];
      dst[2 * i]     = __builtin_shufflevector(a, c, 0, 8, 1, 9, 2, 10, 3, 11);
      dst[2 * i + 1] = __builtin_shufflevector(a, c, 4, 12, 5, 13, 6, 14, 7, 15);
    }
  }
  __syncthreads();
  const int s  = tid & 3;
  const int qb = (tid & 63) & ~3;
  const int slot = start + (tid >> 2);
  if (slot >= end) return;

  const int e = sorted[slot];
  const float f = f_e[e];
  const float fm = 1.f - f;
  const int rec = ei[e], lig = ei[NE + e];
  const float ax = pos[lig * 3 + 0] - pos[rec * 3 + 0];
  const float ay = pos[lig * 3 + 1] - pos[rec * 3 + 1];
  const float az = pos[lig * 3 + 2] - pos[rec * 3 + 2];
  const float d = sqrtf(ax * ax + ay * ay + az * az);
  const float inv = SQ3C / fmaxf(d, 1e-12f);
  const float sh0 = ax * inv, sh1 = ay * inv, sh2 = az * inv;

  // ---- lig features ----
  float s1[16], v1[24];
  {
    const float4* xl = (const float4*)(x + (size_t)lig * 40);
#pragma unroll
    for (int j = 0; j < 4; ++j) {
      float4 v = xl[j];
      s1[j * 4 + 0] = v.x; s1[j * 4 + 1] = v.y; s1[j * 4 + 2] = v.z; s1[j * 4 + 3] = v.w;
    }
#pragma unroll
    for (int j = 0; j < 6; ++j) {
      float4 v = xl[4 + j];
      v1[j * 4 + 0] = v.x; v1[j * 4 + 1] = v.y; v1[j * 4 + 2] = v.z; v1[j * 4 + 3] = v.w;
    }
  }
  float vs[8];
#pragma unroll
  for (int u = 0; u < 8; ++u)
    vs[u] = (v1[u * 3] * sh0 + v1[u * 3 + 1] * sh1 + v1[u * 3 + 2] * sh2) * INV_SQ3;

  // ---- layer 1: sa (lane owns w = 4s..4s+3); lerp folded in fdot2 ----
  float A[4] = {0.f, 0.f, 0.f, 0.f};
#pragma unroll
  for (int u = 0; u < 16; ++u) {   // W000 @ 0
    hp8 w = *(const hp8*)(WP + 2 * (u * 16 + s * 4));
    hp2 sp = pk2(s1[u] * fm, s1[u] * f);
    A[0] = fdot2f(mkh2(w[0], w[1]), sp, A[0]);
    A[1] = fdot2f(mkh2(w[2], w[3]), sp, A[1]);
    A[2] = fdot2f(mkh2(w[4], w[5]), sp, A[2]);
    A[3] = fdot2f(mkh2(w[6], w[7]), sp, A[3]);
  }
#pragma unroll
  for (int u = 0; u < 8; ++u) {    // W110 @ 448
    hp8 w = *(const hp8*)(WP + 2 * (448 + u * 16 + s * 4));
    hp2 sp = pk2(vs[u] * fm, vs[u] * f);
    A[0] = fdot2f(mkh2(w[0], w[1]), sp, A[0]);
    A[1] = fdot2f(mkh2(w[2], w[3]), sp, A[1]);
    A[2] = fdot2f(mkh2(w[4], w[5]), sp, A[2]);
    A[3] = fdot2f(mkh2(w[6], w[7]), sp, A[3]);
  }
  const float sa0 = C0_1F * A[0];
  const float sa1 = C0_1F * A[1];
  const float sa2 = C0_1F * A[2];
  const float sa3 = C0_1F * A[3];

  // ---- layer 1: va (lane owns w = 2s, 2s+1) ----
  float vaA0, vaA1, vaA2, vaB0, vaB1, vaB2;
  {
    float cA = 0.f, cB = 0.f;
#pragma unroll
    for (int u = 0; u < 16; ++u) {  // W011 @ 256
      hp4 w = *(const hp4*)(WP + 2 * (256 + u * 8 + s * 2));
      hp2 sp = pk2(s1[u] * fm, s1[u] * f);
      cA = fdot2f(mkh2(w[0], w[1]), sp, cA);
      cB = fdot2f(mkh2(w[2], w[3]), sp, cB);
    }
    float tAx = 0.f, tAy = 0.f, tAz = 0.f, tBx = 0.f, tBy = 0.f, tBz = 0.f;
#pragma unroll
    for (int u = 0; u < 8; ++u) {   // W101 @ 384
      hp4 w = *(const hp4*)(WP + 2 * (384 + u * 8 + s * 2));
      hp2 px = pk2(v1[u * 3] * fm,     v1[u * 3] * f);
      hp2 py = pk2(v1[u * 3 + 1] * fm, v1[u * 3 + 1] * f);
      hp2 pz = pk2(v1[u * 3 + 2] * fm, v1[u * 3 + 2] * f);
      hp2 pa = mkh2(w[0], w[1]);
      hp2 pb = mkh2(w[2], w[3]);
      tAx = fdot2f(pa, px, tAx); tAy = fdot2f(pa, py, tAy); tAz = fdot2f(pa, pz, tAz);
      tBx = fdot2f(pb, px, tBx); tBy = fdot2f(pb, py, tBy); tBz = fdot2f(pb, pz, tBz);
    }
    vaA0 = C1_1_OS3F * (cA * sh0 + tAx);
    vaA1 = C1_1_OS3F * (cA * sh1 + tAy);
    vaA2 = C1_1_OS3F * (cA * sh2 + tAz);
    vaB0 = C1_1_OS3F * (cB * sh0 + tBx);
    vaB1 = C1_1_OS3F * (cB * sh1 + tBy);
    vaB2 = C1_1_OS3F * (cB * sh2 + tBz);
  }

  // ---- quad allgather ----
  float saF[16];
#pragma unroll
  for (int k = 0; k < 16; ++k) {
    const float v = ((k & 3) == 0) ? sa0 : ((k & 3) == 1) ? sa1 : ((k & 3) == 2) ? sa2 : sa3;
    saF[k] = __shfl(v, qb + (k >> 2), 64);
  }
  float vaF[24];
#pragma unroll
  for (int w = 0; w < 8; ++w) {
    const int src = qb + (w >> 1);
    const float x0 = (w & 1) ? vaB0 : vaA0;
    const float x1 = (w & 1) ? vaB1 : vaA1;
    const float x2 = (w & 1) ? vaB2 : vaA2;
    vaF[w * 3 + 0] = __shfl(x0, src, 64);
    vaF[w * 3 + 1] = __shfl(x1, src, 64);
    vaF[w * 3 + 2] = __shfl(x2, src, 64);
  }

  // ---- rec features: lane's v-subset ----
  const float* xr = x + (size_t)rec * 40;
  const float sbl0 = xr[s],      sbl1 = xr[4 + s];
  const float sbl2 = xr[8 + s],  sbl3 = xr[12 + s];
  const float vbA0 = xr[16 + s * 3 + 0], vbA1 = xr[16 + s * 3 + 1], vbA2 = xr[16 + s * 3 + 2];
  const float vbB0 = xr[16 + (s + 4) * 3 + 0], vbB1 = xr[16 + (s + 4) * 3 + 1], vbB2 = xr[16 + (s + 4) * 3 + 2];

  float oe[20];

  // ===== layer 2: s_out, single pass (lerp in fdot2) =====
  {
    float so[8];
#pragma unroll
    for (int w = 0; w < 8; ++w) so[w] = 0.f;
    // W000 @ 576: [u:16][v:16][w:8], v = vv*4+s
#pragma unroll
    for (int u = 0; u < 16; ++u) {
      const float su = saF[u];
      const __fp16* rp = WP + 2 * (576 + u * 128 + s * 8);
#pragma unroll
      for (int vv = 0; vv < 4; ++vv) {
        const float q = su * ((vv == 0) ? sbl0 : (vv == 1) ? sbl1 : (vv == 2) ? sbl2 : sbl3);
        hp2 qp = pk2(q * fm, q * f);
        hp8 wa = *(const hp8*)(rp + 2 * (vv * 32));
        hp8 wb = *(const hp8*)(rp + 2 * (vv * 32) + 8);
        so[0] = fdot2f(mkh2(wa[0], wa[1]), qp, so[0]);
        so[1] = fdot2f(mkh2(wa[2], wa[3]), qp, so[1]);
        so[2] = fdot2f(mkh2(wa[4], wa[5]), qp, so[2]);
        so[3] = fdot2f(mkh2(wa[6], wa[7]), qp, so[3]);
        so[4] = fdot2f(mkh2(wb[0], wb[1]), qp, so[4]);
        so[5] = fdot2f(mkh2(wb[2], wb[3]), qp, so[5]);
        so[6] = fdot2f(mkh2(wb[4], wb[5]), qp, so[6]);
        so[7] = fdot2f(mkh2(wb[6], wb[7]), qp, so[7]);
      }
    }
    // W110 @ 3648: [u:8][v:8][w:8], v = vv*4+s
#pragma unroll
    for (int u = 0; u < 8; ++u) {
      const float a0 = vaF[u * 3], a1 = vaF[u * 3 + 1], a2 = vaF[u * 3 + 2];
      const __fp16* rp = WP + 2 * (3648 + u * 64 + s * 8);
#pragma unroll
      for (int vv = 0; vv < 2; ++vv) {
        const float b0v = vv ? vbB0 : vbA0;
        const float b1v = vv ? vbB1 : vbA1;
        const float b2v = vv ? vbB2 : vbA2;
        const float dd = (a0 * b0v + a1 * b1v + a2 * b2v) * INV_SQ3;
        hp2 qp = pk2(dd * fm, dd * f);
        hp8 wa = *(const hp8*)(rp + 2 * (vv * 32));
        hp8 wb = *(const hp8*)(rp + 2 * (vv * 32) + 8);
        so[0] = fdot2f(mkh2(wa[0], wa[1]), qp, so[0]);
        so[1] = fdot2f(mkh2(wa[2], wa[3]), qp, so[1]);
        so[2] = fdot2f(mkh2(wa[4], wa[5]), qp, so[2]);
        so[3] = fdot2f(mkh2(wa[6], wa[7]), qp, so[3]);
        so[4] = fdot2f(mkh2(wb[0], wb[1]), qp, so[4]);
        so[5] = fdot2f(mkh2(wb[2], wb[3]), qp, so[5]);
        so[6] = fdot2f(mkh2(wb[4], wb[5]), qp, so[6]);
        so[7] = fdot2f(mkh2(wb[6], wb[7]), qp, so[7]);
      }
    }
#pragma unroll
    for (int w = 0; w < 8; ++w) oe[w] = C0_2F * so[w];
  }

  // ===== layer 2: v_out, single pass =====
  {
    float uo[12];
#pragma unroll
    for (int w = 0; w < 12; ++w) uo[w] = 0.f;
    // W011 @ 2624: [u:16][v:8][w:4], v = vv*4+s
#pragma unroll
    for (int u = 0; u < 16; ++u) {
      const float su = saF[u];
      const __fp16* rp = WP + 2 * (2624 + u * 32 + s * 4);
#pragma unroll
      for (int vv = 0; vv < 2; ++vv) {
        const float q0 = su * (vv ? vbB0 : vbA0);
        const float q1 = su * (vv ? vbB1 : vbA1);
        const float q2 = su * (vv ? vbB2 : vbA2);
        hp2 q0p = pk2(q0 * fm, q0 * f);
        hp2 q1p = pk2(q1 * fm, q1 * f);
        hp2 q2p = pk2(q2 * fm, q2 * f);
        hp8 w = *(const hp8*)(rp + 2 * (vv * 16));
        hp2 p0 = mkh2(w[0], w[1]);
        hp2 p1 = mkh2(w[2], w[3]);
        hp2 p2 = mkh2(w[4], w[5]);
        hp2 p3 = mkh2(w[6], w[7]);
        uo[0] = fdot2f(p0, q0p, uo[0]); uo[1]  = fdot2f(p0, q1p, uo[1]);  uo[2]  = fdot2f(p0, q2p, uo[2]);
        uo[3] = fdot2f(p1, q0p, uo[3]); uo[4]  = fdot2f(p1, q1p, uo[4]);  uo[5]  = fdot2f(p1, q2p, uo[5]);
        uo[6] = fdot2f(p2, q0p, uo[6]); uo[7]  = fdot2f(p2, q1p, uo[7]);  uo[8]  = fdot2f(p2, q2p, uo[8]);
        uo[9] = fdot2f(p3, q0p, uo[9]); uo[10] = fdot2f(p3, q1p, uo[10]); uo[11] = fdot2f(p3, q2p, uo[11]);
      }
    }
    // W101 @ 3136: [u:8][v:16][w:4], v = vv*4+s
#pragma unroll
    for (int u = 0; u < 8; ++u) {
      const float a0 = vaF[u * 3], a1 = vaF[u * 3 + 1], a2 = vaF[u * 3 + 2];
      const __fp16* rp = WP + 2 * (3136 + u * 64 + s * 4);
#pragma unroll
      for (int vv = 0; vv < 4; ++vv) {
        const float sbv = (vv == 0) ? sbl0 : (vv == 1) ? sbl1 : (vv == 2) ? sbl2 : sbl3;
        const float q0 = a0 * sbv, q1 = a1 * sbv, q2 = a2 * sbv;
        hp2 q0p = pk2(q0 * fm, q0 * f);
        hp2 q1p = pk2(q1 * fm, q1 * f);
        hp2 q2p = pk2(q2 * fm, q2 * f);
        hp8 w = *(const hp8*)(rp + 2 * (vv * 16));
        hp2 p0 = mkh2(w[0], w[1]);
        hp2 p1 = mkh2(w[2], w[3]);
        hp2 p2 = mkh2(w[4], w[5]);
        hp2 p3 = mkh2(w[6], w[7]);
        uo[0] = fdot2f(p0, q0p, uo[0]); uo[1]  = fdot2f(p0, q1p, uo[1]);  uo[2]  = fdot2f(p0, q2p, uo[2]);
        uo[3] = fdot2f(p1, q0p, uo[3]); uo[4]  = fdot2f(p1, q1p, uo[4]);  uo[5]  = fdot2f(p1, q2p, uo[5]);
        uo[6] = fdot2f(p2, q0p, uo[6]); uo[7]  = fdot2f(p2, q1p, uo[7]);  uo[8]  = fdot2f(p2, q2p, uo[8]);
        uo[9] = fdot2f(p3, q0p, uo[9]); uo[10] = fdot2f(p3, q1p, uo[10]); uo[11] = fdot2f(p3, q2p, uo[11]);
      }
    }
#pragma unroll
    for (int w = 0; w < 12; ++w) oe[8 + w] = C1_2_OS3F * uo[w];
  }

  // ---- quad butterfly reduce + store ----
#pragma unroll
  for (int w = 0; w < 20; ++w) {
    oe[w] += __shfl_xor(oe[w], 1, 64);
    oe[w] += __shfl_xor(oe[w], 2, 64);
  }
  if (s == 0) {
    float4* op = (float4*)(out + (size_t)e * 20);
#pragma unroll
    for (int j = 0; j < 5; ++j) {
      float4 o4;
      o4.x = oe[j * 4 + 0]; o4.y = oe[j * 4 + 1];
      o4.z = oe[j * 4 + 2]; o4.w = oe[j * 4 + 3];
      op[j] = o4;
    }
  }
}

// ---------------- host ----------------
extern "C" void kernel_launch(void* const* d_in, const int* in_sizes, int n_in,
                              void* d_out, int out_size, void* d_ws, size_t ws_size,
                              hipStream_t stream) {
  const int*   ei  = (const int*)d_in[0];
  const float* pos = (const float*)d_in[1];
  const float* x   = (const float*)d_in[2];
  const float* lw1 = (const float*)d_in[3];
  const float* lw2 = (const float*)d_in[4];
  const float* rw1 = (const float*)d_in[5];
  const float* rw2 = (const float*)d_in[6];
  float* out = (float*)d_out;
  char*  ws  = (char*)d_ws;

  size_t o = 0;
  _Float16* lut = (_Float16*)(ws + o); o += (size_t)NLUT * NC * 2;
  o = (o + 15) & ~(size_t)15;
  _Float16* Hl  = (_Float16*)(ws + o); o += (size_t)MPAD * HDIM * 2;
  _Float16* Hr  = (_Float16*)(ws + o); o += (size_t)MPAD * HDIM * 2;
  _Float16* w2t = (_Float16*)(ws + o); o += (size_t)NC * HDIM * 2;
  o = (o + 15) & ~(size_t)15;
  int*   bin_e = (int*)(ws + o);  o += (size_t)NE * 4;
  float* f_e   = (float*)(ws + o); o += (size_t)NE * 4;
  int*   cnt   = (int*)(ws + o);  o += (size_t)GBIN * 4;
  int*   offs  = (int*)(ws + o);  o += (size_t)(GBIN + 1) * 4 + 12;
  int*   woff  = (int*)(ws + o);  o += (size_t)GBIN * 4;
  int*   sorted = (int*)(ws + o); o += (size_t)NE * 4;
  int*   chunk_bin   = (int*)(ws + o); o += (size_t)NCHMAX * 4;
  int*   chunk_start = (int*)(ws + o); o += (size_t)NCHMAX * 4;
  int*   nch = (int*)(ws + o); o += 16;

  // ACT_C on host (runs at capture time, not in the timed graph)
  double ssum = 0.0;
  const double dz = 20.0 / 40000.0;
  for (int i = 0; i <= 40000; ++i) {
    const double z = -10.0 + dz * (double)i;
    const double sil = z / (1.0 + exp(-z));
    const double phi = exp(-0.5 * z * z) / sqrt(2.0 * M_PI);
    ssum += sil * sil * phi;
  }
  const float actc = (float)(1.0 / sqrt(ssum * dz));
  const float k0c  = (float)(1.14136 * exp(2.0));

  hipMemsetAsync(cnt, 0, GBIN * 4, stream);
  k_fused<<<MPAD + NB_W2T + NB_EDGE, 256, 0, stream>>>(
      lw1, rw1, lw2, rw2, actc, k0c, Hl, Hr, w2t, ei, pos, out, bin_e, f_e, cnt);
  k_lutm<<<dim3(129, 65), 256, 0, stream>>>(Hl, Hr, w2t, lut);
  k_scan<<<1, 256, 0, stream>>>(cnt, offs, woff, chunk_bin, chunk_start, nch);
  k_scatter<<<(NE + 255) / 256, 256, 0, stream>>>(bin_e, woff, sorted);
  k_epi<<<NCHMAX, 128, 0, stream>>>(lut, chunk_bin, chunk_start, offs, sorted, f_e,
                                    ei, pos, x, out, nch);
}

// Round 15
// 104.902 us; speedup vs baseline: 1.1383x; 1.0204x over previous
//
#include <hip/hip_runtime.h>
#include <math.h>

#define NE     50000
#define NNODE  10000
#define HDIM   128
#define GBIN   2048
#define NC     4160          // 576 + 3584
#define NC1    576
#define NCHMAX 3611          // 2048 + ceil(50000/32)
#define MPAD   2064          // 129*16 padded grid rows
#define NB_W2T 1040          // (64*NC)/256
#define NB_EDGE 196          // ceil(NE/256)
#define NB_GEMM (129*65)

typedef _Float16 h2 __attribute__((ext_vector_type(2)));
typedef _Float16 h8 __attribute__((ext_vector_type(8)));
typedef float f32x4 __attribute__((ext_vector_type(4)));

typedef __fp16 hp2 __attribute__((ext_vector_type(2)));
typedef __fp16 hp4 __attribute__((ext_vector_type(4)));
typedef __fp16 hp8 __attribute__((ext_vector_type(8)));

static __device__ __forceinline__ float fdot2f(hp2 p, hp2 q, float acc) {
  return __builtin_amdgcn_fdot2(p, q, acc, false);
}
static __device__ __forceinline__ hp2 pk2(float a, float b) {
  hp2 r = __builtin_amdgcn_cvt_pkrtz(a, b);
  return r;
}
static __device__ __forceinline__ hp2 mkh2(__fp16 a, __fp16 b) {
  hp2 o; o[0] = a; o[1] = b;
  return o;
}

// constants
#define SQ3C        1.7320508075688772f
#define INV_SQ3     0.5773502691896258f
#define C0_1F       0.20412414523193154f   // 1/sqrt(24)
#define C1_1_OS3F   0.20412414523193154f   // sqrt(3/24)/sqrt(3)
#define C0_2F       0.05590169943749474f   // 1/sqrt(320)
#define C1_2_OS3F   0.0625f                // sqrt(3/256)/sqrt(3)
#define INV_SQRT_H  0.08838834764831845f   // 1/sqrt(128)
#define DELTA       (5.0f/2048.0f)
#define INV_DELTA   409.6f
#define STEP_INV    (51.0f/5.0f)

// ---------------- K1: fused prologue ----------------
__global__ __launch_bounds__(256) void k_fused(
    const float* __restrict__ lw1, const float* __restrict__ rw1,
    const float* __restrict__ lw2, const float* __restrict__ rw2,
    const float actc, const float K0C,
    _Float16* __restrict__ Hl, _Float16* __restrict__ Hr,
    _Float16* __restrict__ w2t,
    const int* __restrict__ ei, const float* __restrict__ pos,
    float* __restrict__ out, int* __restrict__ bin_e,
    float* __restrict__ f_e, int* __restrict__ cnt) {
  const int bid = blockIdx.x;
  const int tid = threadIdx.x;
  if (bid < MPAD) {
    const int g = bid;
    const int which = tid >> 7, hc = tid & 127;
    const float* __restrict__ w1 = which ? rw1 : lw1;
    float h = 0.f;
    if (g <= GBIN) {
      const float tt = (float)g * DELTA * STEP_INV;
      const int i0 = (int)floorf(tt);
      float z = 0.f;
#pragma unroll
      for (int k = 0; k < 2; ++k) {
        const int ii = i0 + k;
        if (ii >= 1 && ii <= 50) {
          const float diff = tt - (float)ii;
          const float a = diff + 1.f, b = 1.f - diff;
          if (a > 0.f && b > 0.f) {
            const float val = K0C * __expf(-1.f / a - 1.f / b);
            z += val * w1[(ii - 1) * HDIM + hc];
          }
        }
      }
      h = actc * z / (1.f + __expf(-z)) * INV_SQRT_H;
    }
    _Float16* __restrict__ H = which ? Hr : Hl;
    H[(size_t)g * HDIM + hc] = (_Float16)h;
  } else if (bid < MPAD + NB_W2T) {
    const int gid = (bid - MPAD) * 256 + tid;
    const int k2 = gid / NC;
    const int n  = gid - k2 * NC;
    float a, b;
    if (n < NC1) {
      a = lw2[(size_t)(2 * k2) * NC1 + n];
      b = lw2[(size_t)(2 * k2 + 1) * NC1 + n];
    } else {
      const int m = n - NC1;
      a = rw2[(size_t)(2 * k2) * 3584 + m];
      b = rw2[(size_t)(2 * k2 + 1) * 3584 + m];
    }
    h2 p; p[0] = (_Float16)a; p[1] = (_Float16)b;
    *(h2*)(w2t + (size_t)n * HDIM + 2 * k2) = p;
  } else {
    const int e = (bid - MPAD - NB_W2T) * 256 + tid;
    if (e >= NE) return;
    const int rec = ei[e], lig = ei[NE + e];
    const float ax = pos[lig * 3 + 0] - pos[rec * 3 + 0];
    const float ay = pos[lig * 3 + 1] - pos[rec * 3 + 1];
    const float az = pos[lig * 3 + 2] - pos[rec * 3 + 2];
    const float d = sqrtf(ax * ax + ay * ay + az * az);
    if (d > 0.f && d < 5.0f) {
      const float tf = d * INV_DELTA;
      int b = (int)tf;
      if (b > GBIN - 1) b = GBIN - 1;
      bin_e[e] = b;
      f_e[e] = tf - (float)b;
      atomicAdd(&cnt[b], 1);
    } else {
      bin_e[e] = -1;
      float* o = out + (size_t)e * 20;
#pragma unroll
      for (int i2 = 0; i2 < 20; ++i2) o[i2] = 0.f;
    }
  }
}

// ---------------- K2: LUT GEMM (pair-interleaved output) + scan block ----------------
// blocks [0, NB_GEMM): one 16x16 MFMA tile; each value stored to ilut[g] lo and ilut[g-1] hi.
// block NB_GEMM: scan + chunk-table emission (single block; needs cnt from k_fused).
__global__ __launch_bounds__(256) void k_lutm(
    const _Float16* __restrict__ Hl, const _Float16* __restrict__ Hr,
    const _Float16* __restrict__ w2t, __fp16* __restrict__ ilut,
    const int* __restrict__ cnt, int* __restrict__ offs,
    int* __restrict__ woff, int* __restrict__ chunk_bin,
    int* __restrict__ chunk_start, int* __restrict__ nch) {
  const int bid = blockIdx.x;
  const int tid = threadIdx.x;
  if (bid < NB_GEMM) {
    const int mt = bid % 129;
    const int nt = (bid / 129) * 4 + (tid >> 6);   // 0..259
    const int l  = tid & 63;
    const int rc = l & 15;
    const int kg = (l >> 4) * 8;
    const _Float16* __restrict__ Ap =
        ((nt < 36) ? Hl : Hr) + (size_t)(mt * 16 + rc) * HDIM + kg;
    const _Float16* __restrict__ Bp = w2t + (size_t)(nt * 16 + rc) * HDIM + kg;
    f32x4 acc = {0.f, 0.f, 0.f, 0.f};
#pragma unroll
    for (int kc = 0; kc < 4; ++kc) {
      h8 a = *(const h8*)(Ap + kc * 32);
      h8 b = *(const h8*)(Bp + kc * 32);
      acc = __builtin_amdgcn_mfma_f32_16x16x32_f16(a, b, acc, 0, 0, 0);
    }
    const int n = nt * 16 + rc;
#pragma unroll
    for (int r = 0; r < 4; ++r) {
      const int g = mt * 16 + (l >> 4) * 4 + r;
      if (g <= GBIN) {
        const __fp16 v = (__fp16)acc[r];
        if (g < GBIN) ilut[(size_t)g * (2 * NC) + 2 * n] = v;            // row g, lo
        if (g >= 1)   ilut[(size_t)(g - 1) * (2 * NC) + 2 * n + 1] = v;  // row g-1, hi
      }
    }
  } else {
    // ---- scan + chunk emission ----
    __shared__ int lds[256];
    const int t = tid;
    int loc[8];
    int s = 0;
#pragma unroll
    for (int i = 0; i < 8; ++i) { loc[i] = cnt[t * 8 + i]; s += loc[i]; }
    lds[t] = s;
    __syncthreads();
    for (int o = 1; o < 256; o <<= 1) {
      int v = 0;
      if (t >= o) v = lds[t - o];
      __syncthreads();
      lds[t] += v;
      __syncthreads();
    }
    int run = lds[t] - s;
    int runs[8];
#pragma unroll
    for (int i = 0; i < 8; ++i) {
      runs[i] = run;
      offs[t * 8 + i] = run;
      woff[t * 8 + i] = run;
      run += loc[i];
    }
    if (t == 255) offs[GBIN] = run;

    int ccnt[8];
    int csum = 0;
#pragma unroll
    for (int i = 0; i < 8; ++i) { ccnt[i] = (loc[i] + 31) >> 5; csum += ccnt[i]; }
    __syncthreads();
    lds[t] = csum;
    __syncthreads();
    for (int o = 1; o < 256; o <<= 1) {
      int v = 0;
      if (t >= o) v = lds[t - o];
      __syncthreads();
      lds[t] += v;
      __syncthreads();
    }
    int crun = lds[t] - csum;
#pragma unroll
    for (int i = 0; i < 8; ++i) {
      for (int c = 0; c < ccnt[i]; ++c) {
        chunk_bin[crun]   = t * 8 + i;
        chunk_start[crun] = runs[i] + c * 32;
        ++crun;
      }
    }
    if (t == 255) nch[0] = lds[255];
  }
}

// ---------------- K3: counting-sort scatter ----------------
__global__ void k_scatter(const int* __restrict__ bin_e, int* __restrict__ woff,
                          int* __restrict__ sorted) {
  const int e = blockIdx.x * 256 + threadIdx.x;
  if (e >= NE) return;
  const int b = bin_e[e];
  if (b >= 0) {
    const int p = atomicAdd(&woff[b], 1);
    sorted[p] = e;
  }
}

// ---------------- K4: epilogue: 32-edge chunk / 128 threads; pair LDS via linear copy ----
__global__ __launch_bounds__(128) void k_epi(
    const __fp16* __restrict__ ilut, const int* __restrict__ chunk_bin,
    const int* __restrict__ chunk_start, const int* __restrict__ offs,
    const int* __restrict__ sorted, const float* __restrict__ f_e,
    const int* __restrict__ ei, const float* __restrict__ pos,
    const float* __restrict__ x, float* __restrict__ out,
    const int* __restrict__ nch) {
  __shared__ __fp16 WP[2 * NC];        // 16640 B
  const int bid = blockIdx.x;
  if (bid >= nch[0]) return;
  const int b     = chunk_bin[bid];
  const int start = chunk_start[bid];
  const int end0  = offs[b + 1];
  const int end   = (start + 32 < end0) ? (start + 32) : end0;
  const int tid = threadIdx.x;
  {  // stage: linear copy of pre-interleaved row (1040 x uint4)
    const uint4* src = (const uint4*)(ilut + (size_t)b * (2 * NC));
    uint4* dst = (uint4*)WP;
    for (int i = tid; i < 1040; i += 128) dst[i] = src[i];
  }
  __syncthreads();
  const int s  = tid & 3;
  const int qb = (tid & 63) & ~3;
  const int slot = start + (tid >> 2);
  if (slot >= end) return;

  const int e = sorted[slot];
  const float f = f_e[e];
  const float fm = 1.f - f;
  const int rec = ei[e], lig = ei[NE + e];
  const float ax = pos[lig * 3 + 0] - pos[rec * 3 + 0];
  const float ay = pos[lig * 3 + 1] - pos[rec * 3 + 1];
  const float az = pos[lig * 3 + 2] - pos[rec * 3 + 2];
  const float d = sqrtf(ax * ax + ay * ay + az * az);
  const float inv = SQ3C / fmaxf(d, 1e-12f);
  const float sh0 = ax * inv, sh1 = ay * inv, sh2 = az * inv;

  // ---- lig features ----
  float s1[16], v1[24];
  {
    const float4* xl = (const float4*)(x + (size_t)lig * 40);
#pragma unroll
    for (int j = 0; j < 4; ++j) {
      float4 v = xl[j];
      s1[j * 4 + 0] = v.x; s1[j * 4 + 1] = v.y; s1[j * 4 + 2] = v.z; s1[j * 4 + 3] = v.w;
    }
#pragma unroll
    for (int j = 0; j < 6; ++j) {
      float4 v = xl[4 + j];
      v1[j * 4 + 0] = v.x; v1[j * 4 + 1] = v.y; v1[j * 4 + 2] = v.z; v1[j * 4 + 3] = v.w;
    }
  }
  float vs[8];
#pragma unroll
  for (int u = 0; u < 8; ++u)
    vs[u] = (v1[u * 3] * sh0 + v1[u * 3 + 1] * sh1 + v1[u * 3 + 2] * sh2) * INV_SQ3;

  // ---- layer 1: sa (lane owns w = 4s..4s+3); lerp folded in fdot2 ----
  float A[4] = {0.f, 0.f, 0.f, 0.f};
#pragma unroll
  for (int u = 0; u < 16; ++u) {   // W000 @ 0
    hp8 w = *(const hp8*)(WP + 2 * (u * 16 + s * 4));
    hp2 sp = pk2(s1[u] * fm, s1[u] * f);
    A[0] = fdot2f(mkh2(w[0], w[1]), sp, A[0]);
    A[1] = fdot2f(mkh2(w[2], w[3]), sp, A[1]);
    A[2] = fdot2f(mkh2(w[4], w[5]), sp, A[2]);
    A[3] = fdot2f(mkh2(w[6], w[7]), sp, A[3]);
  }
#pragma unroll
  for (int u = 0; u < 8; ++u) {    // W110 @ 448
    hp8 w = *(const hp8*)(WP + 2 * (448 + u * 16 + s * 4));
    hp2 sp = pk2(vs[u] * fm, vs[u] * f);
    A[0] = fdot2f(mkh2(w[0], w[1]), sp, A[0]);
    A[1] = fdot2f(mkh2(w[2], w[3]), sp, A[1]);
    A[2] = fdot2f(mkh2(w[4], w[5]), sp, A[2]);
    A[3] = fdot2f(mkh2(w[6], w[7]), sp, A[3]);
  }
  const float sa0 = C0_1F * A[0];
  const float sa1 = C0_1F * A[1];
  const float sa2 = C0_1F * A[2];
  const float sa3 = C0_1F * A[3];

  // ---- layer 1: va (lane owns w = 2s, 2s+1) ----
  float vaA0, vaA1, vaA2, vaB0, vaB1, vaB2;
  {
    float cA = 0.f, cB = 0.f;
#pragma unroll
    for (int u = 0; u < 16; ++u) {  // W011 @ 256
      hp4 w = *(const hp4*)(WP + 2 * (256 + u * 8 + s * 2));
      hp2 sp = pk2(s1[u] * fm, s1[u] * f);
      cA = fdot2f(mkh2(w[0], w[1]), sp, cA);
      cB = fdot2f(mkh2(w[2], w[3]), sp, cB);
    }
    float tAx = 0.f, tAy = 0.f, tAz = 0.f, tBx = 0.f, tBy = 0.f, tBz = 0.f;
#pragma unroll
    for (int u = 0; u < 8; ++u) {   // W101 @ 384
      hp4 w = *(const hp4*)(WP + 2 * (384 + u * 8 + s * 2));
      hp2 px = pk2(v1[u * 3] * fm,     v1[u * 3] * f);
      hp2 py = pk2(v1[u * 3 + 1] * fm, v1[u * 3 + 1] * f);
      hp2 pz = pk2(v1[u * 3 + 2] * fm, v1[u * 3 + 2] * f);
      hp2 pa = mkh2(w[0], w[1]);
      hp2 pb = mkh2(w[2], w[3]);
      tAx = fdot2f(pa, px, tAx); tAy = fdot2f(pa, py, tAy); tAz = fdot2f(pa, pz, tAz);
      tBx = fdot2f(pb, px, tBx); tBy = fdot2f(pb, py, tBy); tBz = fdot2f(pb, pz, tBz);
    }
    vaA0 = C1_1_OS3F * (cA * sh0 + tAx);
    vaA1 = C1_1_OS3F * (cA * sh1 + tAy);
    vaA2 = C1_1_OS3F * (cA * sh2 + tAz);
    vaB0 = C1_1_OS3F * (cB * sh0 + tBx);
    vaB1 = C1_1_OS3F * (cB * sh1 + tBy);
    vaB2 = C1_1_OS3F * (cB * sh2 + tBz);
  }

  // ---- quad allgather ----
  float saF[16];
#pragma unroll
  for (int k = 0; k < 16; ++k) {
    const float v = ((k & 3) == 0) ? sa0 : ((k & 3) == 1) ? sa1 : ((k & 3) == 2) ? sa2 : sa3;
    saF[k] = __shfl(v, qb + (k >> 2), 64);
  }
  float vaF[24];
#pragma unroll
  for (int w = 0; w < 8; ++w) {
    const int src = qb + (w >> 1);
    const float x0 = (w & 1) ? vaB0 : vaA0;
    const float x1 = (w & 1) ? vaB1 : vaA1;
    const float x2 = (w & 1) ? vaB2 : vaA2;
    vaF[w * 3 + 0] = __shfl(x0, src, 64);
    vaF[w * 3 + 1] = __shfl(x1, src, 64);
    vaF[w * 3 + 2] = __shfl(x2, src, 64);
  }

  // ---- rec features: lane's v-subset ----
  const float* xr = x + (size_t)rec * 40;
  const float sbl0 = xr[s],      sbl1 = xr[4 + s];
  const float sbl2 = xr[8 + s],  sbl3 = xr[12 + s];
  const float vbA0 = xr[16 + s * 3 + 0], vbA1 = xr[16 + s * 3 + 1], vbA2 = xr[16 + s * 3 + 2];
  const float vbB0 = xr[16 + (s + 4) * 3 + 0], vbB1 = xr[16 + (s + 4) * 3 + 1], vbB2 = xr[16 + (s + 4) * 3 + 2];

  float oe[20];

  // ===== layer 2: s_out =====
  {
    float so[8];
#pragma unroll
    for (int w = 0; w < 8; ++w) so[w] = 0.f;
#pragma unroll
    for (int u = 0; u < 16; ++u) {   // W000 @ 576: [u:16][v:16][w:8], v = vv*4+s
      const float su = saF[u];
      const __fp16* rp = WP + 2 * (576 + u * 128 + s * 8);
#pragma unroll
      for (int vv = 0; vv < 4; ++vv) {
        const float q = su * ((vv == 0) ? sbl0 : (vv == 1) ? sbl1 : (vv == 2) ? sbl2 : sbl3);
        hp2 qp = pk2(q * fm, q * f);
        hp8 wa = *(const hp8*)(rp + 2 * (vv * 32));
        hp8 wb = *(const hp8*)(rp + 2 * (vv * 32) + 8);
        so[0] = fdot2f(mkh2(wa[0], wa[1]), qp, so[0]);
        so[1] = fdot2f(mkh2(wa[2], wa[3]), qp, so[1]);
        so[2] = fdot2f(mkh2(wa[4], wa[5]), qp, so[2]);
        so[3] = fdot2f(mkh2(wa[6], wa[7]), qp, so[3]);
        so[4] = fdot2f(mkh2(wb[0], wb[1]), qp, so[4]);
        so[5] = fdot2f(mkh2(wb[2], wb[3]), qp, so[5]);
        so[6] = fdot2f(mkh2(wb[4], wb[5]), qp, so[6]);
        so[7] = fdot2f(mkh2(wb[6], wb[7]), qp, so[7]);
      }
    }
#pragma unroll
    for (int u = 0; u < 8; ++u) {    // W110 @ 3648: [u:8][v:8][w:8], v = vv*4+s
      const float a0 = vaF[u * 3], a1 = vaF[u * 3 + 1], a2 = vaF[u * 3 + 2];
      const __fp16* rp = WP + 2 * (3648 + u * 64 + s * 8);
#pragma unroll
      for (int vv = 0; vv < 2; ++vv) {
        const float b0v = vv ? vbB0 : vbA0;
        const float b1v = vv ? vbB1 : vbA1;
        const float b2v = vv ? vbB2 : vbA2;
        const float dd = (a0 * b0v + a1 * b1v + a2 * b2v) * INV_SQ3;
        hp2 qp = pk2(dd * fm, dd * f);
        hp8 wa = *(const hp8*)(rp + 2 * (vv * 32));
        hp8 wb = *(const hp8*)(rp + 2 * (vv * 32) + 8);
        so[0] = fdot2f(mkh2(wa[0], wa[1]), qp, so[0]);
        so[1] = fdot2f(mkh2(wa[2], wa[3]), qp, so[1]);
        so[2] = fdot2f(mkh2(wa[4], wa[5]), qp, so[2]);
        so[3] = fdot2f(mkh2(wa[6], wa[7]), qp, so[3]);
        so[4] = fdot2f(mkh2(wb[0], wb[1]), qp, so[4]);
        so[5] = fdot2f(mkh2(wb[2], wb[3]), qp, so[5]);
        so[6] = fdot2f(mkh2(wb[4], wb[5]), qp, so[6]);
        so[7] = fdot2f(mkh2(wb[6], wb[7]), qp, so[7]);
      }
    }
#pragma unroll
    for (int w = 0; w < 8; ++w) oe[w] = C0_2F * so[w];
  }

  // ===== layer 2: v_out =====
  {
    float uo[12];
#pragma unroll
    for (int w = 0; w < 12; ++w) uo[w] = 0.f;
#pragma unroll
    for (int u = 0; u < 16; ++u) {   // W011 @ 2624: [u:16][v:8][w:4], v = vv*4+s
      const float su = saF[u];
      const __fp16* rp = WP + 2 * (2624 + u * 32 + s * 4);
#pragma unroll
      for (int vv = 0; vv < 2; ++vv) {
        const float q0 = su * (vv ? vbB0 : vbA0);
        const float q1 = su * (vv ? vbB1 : vbA1);
        const float q2 = su * (vv ? vbB2 : vbA2);
        hp2 q0p = pk2(q0 * fm, q0 * f);
        hp2 q1p = pk2(q1 * fm, q1 * f);
        hp2 q2p = pk2(q2 * fm, q2 * f);
        hp8 w = *(const hp8*)(rp + 2 * (vv * 16));
        hp2 p0 = mkh2(w[0], w[1]);
        hp2 p1 = mkh2(w[2], w[3]);
        hp2 p2 = mkh2(w[4], w[5]);
        hp2 p3 = mkh2(w[6], w[7]);
        uo[0] = fdot2f(p0, q0p, uo[0]); uo[1]  = fdot2f(p0, q1p, uo[1]);  uo[2]  = fdot2f(p0, q2p, uo[2]);
        uo[3] = fdot2f(p1, q0p, uo[3]); uo[4]  = fdot2f(p1, q1p, uo[4]);  uo[5]  = fdot2f(p1, q2p, uo[5]);
        uo[6] = fdot2f(p2, q0p, uo[6]); uo[7]  = fdot2f(p2, q1p, uo[7]);  uo[8]  = fdot2f(p2, q2p, uo[8]);
        uo[9] = fdot2f(p3, q0p, uo[9]); uo[10] = fdot2f(p3, q1p, uo[10]); uo[11] = fdot2f(p3, q2p, uo[11]);
      }
    }
#pragma unroll
    for (int u = 0; u < 8; ++u) {    // W101 @ 3136: [u:8][v:16][w:4], v = vv*4+s
      const float a0 = vaF[u * 3], a1 = vaF[u * 3 + 1], a2 = vaF[u * 3 + 2];
      const __fp16* rp = WP + 2 * (3136 + u * 64 + s * 4);
#pragma unroll
      for (int vv = 0; vv < 4; ++vv) {
        const float sbv = (vv == 0) ? sbl0 : (vv == 1) ? sbl1 : (vv == 2) ? sbl2 : sbl3;
        const float q0 = a0 * sbv, q1 = a1 * sbv, q2 = a2 * sbv;
        hp2 q0p = pk2(q0 * fm, q0 * f);
        hp2 q1p = pk2(q1 * fm, q1 * f);
        hp2 q2p = pk2(q2 * fm, q2 * f);
        hp8 w = *(const hp8*)(rp + 2 * (vv * 16));
        hp2 p0 = mkh2(w[0], w[1]);
        hp2 p1 = mkh2(w[2], w[3]);
        hp2 p2 = mkh2(w[4], w[5]);
        hp2 p3 = mkh2(w[6], w[7]);
        uo[0] = fdot2f(p0, q0p, uo[0]); uo[1]  = fdot2f(p0, q1p, uo[1]);  uo[2]  = fdot2f(p0, q2p, uo[2]);
        uo[3] = fdot2f(p1, q0p, uo[3]); uo[4]  = fdot2f(p1, q1p, uo[4]);  uo[5]  = fdot2f(p1, q2p, uo[5]);
        uo[6] = fdot2f(p2, q0p, uo[6]); uo[7]  = fdot2f(p2, q1p, uo[7]);  uo[8]  = fdot2f(p2, q2p, uo[8]);
        uo[9] = fdot2f(p3, q0p, uo[9]); uo[10] = fdot2f(p3, q1p, uo[10]); uo[11] = fdot2f(p3, q2p, uo[11]);
      }
    }
#pragma unroll
    for (int w = 0; w < 12; ++w) oe[8 + w] = C1_2_OS3F * uo[w];
  }

  // ---- quad butterfly reduce + store ----
#pragma unroll
  for (int w = 0; w < 20; ++w) {
    oe[w] += __shfl_xor(oe[w], 1, 64);
    oe[w] += __shfl_xor(oe[w], 2, 64);
  }
  if (s == 0) {
    float4* op = (float4*)(out + (size_t)e * 20);
#pragma unroll
    for (int j = 0; j < 5; ++j) {
      float4 o4;
      o4.x = oe[j * 4 + 0]; o4.y = oe[j * 4 + 1];
      o4.z = oe[j * 4 + 2]; o4.w = oe[j * 4 + 3];
      op[j] = o4;
    }
  }
}

// ---------------- host ----------------
extern "C" void kernel_launch(void* const* d_in, const int* in_sizes, int n_in,
                              void* d_out, int out_size, void* d_ws, size_t ws_size,
                              hipStream_t stream) {
  const int*   ei  = (const int*)d_in[0];
  const float* pos = (const float*)d_in[1];
  const float* x   = (const float*)d_in[2];
  const float* lw1 = (const float*)d_in[3];
  const float* lw2 = (const float*)d_in[4];
  const float* rw1 = (const float*)d_in[5];
  const float* rw2 = (const float*)d_in[6];
  float* out = (float*)d_out;
  char*  ws  = (char*)d_ws;

  size_t o = 0;
  __fp16* ilut = (__fp16*)(ws + o); o += (size_t)GBIN * (2 * NC) * 2;
  o = (o + 15) & ~(size_t)15;
  _Float16* Hl  = (_Float16*)(ws + o); o += (size_t)MPAD * HDIM * 2;
  _Float16* Hr  = (_Float16*)(ws + o); o += (size_t)MPAD * HDIM * 2;
  _Float16* w2t = (_Float16*)(ws + o); o += (size_t)NC * HDIM * 2;
  o = (o + 15) & ~(size_t)15;
  int*   bin_e = (int*)(ws + o);  o += (size_t)NE * 4;
  float* f_e   = (float*)(ws + o); o += (size_t)NE * 4;
  int*   cnt   = (int*)(ws + o);  o += (size_t)GBIN * 4;
  int*   offs  = (int*)(ws + o);  o += (size_t)(GBIN + 1) * 4 + 12;
  int*   woff  = (int*)(ws + o);  o += (size_t)GBIN * 4;
  int*   sorted = (int*)(ws + o); o += (size_t)NE * 4;
  int*   chunk_bin   = (int*)(ws + o); o += (size_t)NCHMAX * 4;
  int*   chunk_start = (int*)(ws + o); o += (size_t)NCHMAX * 4;
  int*   nch = (int*)(ws + o); o += 16;

  // ACT_C on host (runs at capture time, not in the timed graph)
  double ssum = 0.0;
  const double dz = 20.0 / 40000.0;
  for (int i = 0; i <= 40000; ++i) {
    const double z = -10.0 + dz * (double)i;
    const double sil = z / (1.0 + exp(-z));
    const double phi = exp(-0.5 * z * z) / sqrt(2.0 * M_PI);
    ssum += sil * sil * phi;
  }
  const float actc = (float)(1.0 / sqrt(ssum * dz));
  const float k0c  = (float)(1.14136 * exp(2.0));

  hipMemsetAsync(cnt, 0, GBIN * 4, stream);
  k_fused<<<MPAD + NB_W2T + NB_EDGE, 256, 0, stream>>>(
      lw1, rw1, lw2, rw2, actc, k0c, Hl, Hr, w2t, ei, pos, out, bin_e, f_e, cnt);
  k_lutm<<<NB_GEMM + 1, 256, 0, stream>>>(Hl, Hr, w2t, ilut, cnt, offs, woff,
                                          chunk_bin, chunk_start, nch);
  k_scatter<<<(NE + 255) / 256, 256, 0, stream>>>(bin_e, woff, sorted);
  k_epi<<<NCHMAX, 128, 0, stream>>>(ilut, chunk_bin, chunk_start, offs, sorted, f_e,
                                    ei, pos, x, out, nch);
}

// Round 16
// 102.559 us; speedup vs baseline: 1.1643x; 1.0228x over previous
//
#include <hip/hip_runtime.h>
#include <math.h>

#define NE     50000
#define NNODE  10000
#define HDIM   128
#define GBIN   2048
#define NC     4160          // 576 + 3584
#define NC1    576
#define NCHMAX 3611          // 2048 + ceil(50000/32)
#define MPAD   2064          // 129*16 padded grid rows
#define NB_W2T 65            // 65 transpose tiles of 64 columns
#define NB_EDGE 196          // ceil(NE/256)
#define NB_GEMM (129*65)

typedef _Float16 h2 __attribute__((ext_vector_type(2)));
typedef _Float16 h8 __attribute__((ext_vector_type(8)));
typedef float f32x4 __attribute__((ext_vector_type(4)));

typedef __fp16 hp2 __attribute__((ext_vector_type(2)));
typedef __fp16 hp4 __attribute__((ext_vector_type(4)));
typedef __fp16 hp8 __attribute__((ext_vector_type(8)));

static __device__ __forceinline__ float fdot2f(hp2 p, hp2 q, float acc) {
  return __builtin_amdgcn_fdot2(p, q, acc, false);
}
static __device__ __forceinline__ hp2 pk2(float a, float b) {
  hp2 r = __builtin_amdgcn_cvt_pkrtz(a, b);
  return r;
}
static __device__ __forceinline__ hp2 mkh2(__fp16 a, __fp16 b) {
  hp2 o; o[0] = a; o[1] = b;
  return o;
}

// constants
#define SQ3C        1.7320508075688772f
#define INV_SQ3     0.5773502691896258f
#define C0_1F       0.20412414523193154f   // 1/sqrt(24)
#define C1_1_OS3F   0.20412414523193154f   // sqrt(3/24)/sqrt(3)
#define C0_2F       0.05590169943749474f   // 1/sqrt(320)
#define C1_2_OS3F   0.0625f                // sqrt(3/256)/sqrt(3)
#define INV_SQRT_H  0.08838834764831845f   // 1/sqrt(128)
#define DELTA       (5.0f/2048.0f)
#define INV_DELTA   409.6f
#define STEP_INV    (51.0f/5.0f)

// ---------------- K1: fused prologue ----------------
// blocks [0, MPAD)            : H activations (fp16), both MLPs
// blocks [MPAD, MPAD+65)      : W2 -> W2T via LDS-tiled transpose (64 cols/block)
// blocks [MPAD+65, +NB_EDGE)  : per-edge bin/frac + histogram + zero inactive
__global__ __launch_bounds__(256) void k_fused(
    const float* __restrict__ lw1, const float* __restrict__ rw1,
    const float* __restrict__ lw2, const float* __restrict__ rw2,
    const float actc, const float K0C,
    _Float16* __restrict__ Hl, _Float16* __restrict__ Hr,
    _Float16* __restrict__ w2t,
    const int* __restrict__ ei, const float* __restrict__ pos,
    float* __restrict__ out, int* __restrict__ bin_e,
    float* __restrict__ f_e, int* __restrict__ cnt) {
  __shared__ _Float16 TT[64 * 136];   // 17408 B (transpose tile)
  const int bid = blockIdx.x;
  const int tid = threadIdx.x;
  if (bid < MPAD) {
    const int g = bid;
    const int which = tid >> 7, hc = tid & 127;
    const float* __restrict__ w1 = which ? rw1 : lw1;
    float h = 0.f;
    if (g <= GBIN) {
      const float tt = (float)g * DELTA * STEP_INV;
      const int i0 = (int)floorf(tt);
      float z = 0.f;
#pragma unroll
      for (int k = 0; k < 2; ++k) {
        const int ii = i0 + k;
        if (ii >= 1 && ii <= 50) {
          const float diff = tt - (float)ii;
          const float a = diff + 1.f, b = 1.f - diff;
          if (a > 0.f && b > 0.f) {
            const float val = K0C * __expf(-1.f / a - 1.f / b);
            z += val * w1[(ii - 1) * HDIM + hc];
          }
        }
      }
      h = actc * z / (1.f + __expf(-z)) * INV_SQRT_H;
    }
    _Float16* __restrict__ H = which ? Hr : Hl;
    H[(size_t)g * HDIM + hc] = (_Float16)h;
  } else if (bid < MPAD + NB_W2T) {
    // ---- W2T: tile of 64 columns x 128 k ----
    const int b = bid - MPAD;
    const int n0 = b * 64;
    const int isrec = (n0 >= NC1);
    const float* __restrict__ src = isrec ? rw2 : lw2;
    const int ncols = isrec ? 3584 : NC1;
    const int c0 = isrec ? (n0 - NC1) : n0;
    // phase 1: coalesced row reads -> transposed LDS
#pragma unroll
    for (int i = 0; i < 32; ++i) {
      const int idx = i * 256 + tid;
      const int k = idx >> 6;
      const int j = idx & 63;
      TT[j * 136 + k] = (_Float16)src[(size_t)k * ncols + c0 + j];
    }
    __syncthreads();
    // phase 2: coalesced h8 writes
#pragma unroll
    for (int it = 0; it < 4; ++it) {
      const int jj = it * 16 + (tid >> 4);
      const int kc = tid & 15;
      h8 w = *(const h8*)&TT[jj * 136 + kc * 8];
      *(h8*)(w2t + (size_t)(n0 + jj) * HDIM + kc * 8) = w;
    }
  } else {
    const int e = (bid - MPAD - NB_W2T) * 256 + tid;
    if (e >= NE) return;
    const int rec = ei[e], lig = ei[NE + e];
    const float ax = pos[lig * 3 + 0] - pos[rec * 3 + 0];
    const float ay = pos[lig * 3 + 1] - pos[rec * 3 + 1];
    const float az = pos[lig * 3 + 2] - pos[rec * 3 + 2];
    const float d = sqrtf(ax * ax + ay * ay + az * az);
    if (d > 0.f && d < 5.0f) {
      const float tf = d * INV_DELTA;
      int b = (int)tf;
      if (b > GBIN - 1) b = GBIN - 1;
      bin_e[e] = b;
      f_e[e] = tf - (float)b;
      atomicAdd(&cnt[b], 1);
    } else {
      bin_e[e] = -1;
      float* o = out + (size_t)e * 20;
#pragma unroll
      for (int i2 = 0; i2 < 20; ++i2) o[i2] = 0.f;
    }
  }
}

// ---------------- K2: LUT GEMM (pair-interleaved output, 4B pair stores) + scan ----------
__global__ __launch_bounds__(256) void k_lutm(
    const _Float16* __restrict__ Hl, const _Float16* __restrict__ Hr,
    const _Float16* __restrict__ w2t, __fp16* __restrict__ ilut,
    const int* __restrict__ cnt, int* __restrict__ offs,
    int* __restrict__ woff, int* __restrict__ chunk_bin,
    int* __restrict__ chunk_start, int* __restrict__ nch) {
  const int bid = blockIdx.x;
  const int tid = threadIdx.x;
  if (bid < NB_GEMM) {
    const int mt = bid % 129;
    const int nt = (bid / 129) * 4 + (tid >> 6);   // 0..259
    const int l  = tid & 63;
    const int rc = l & 15;
    const int kg = (l >> 4) * 8;
    const _Float16* __restrict__ Ap =
        ((nt < 36) ? Hl : Hr) + (size_t)(mt * 16 + rc) * HDIM + kg;
    const _Float16* __restrict__ Bp = w2t + (size_t)(nt * 16 + rc) * HDIM + kg;
    f32x4 acc = {0.f, 0.f, 0.f, 0.f};
#pragma unroll
    for (int kc = 0; kc < 4; ++kc) {
      h8 a = *(const h8*)(Ap + kc * 32);
      h8 b = *(const h8*)(Bp + kc * 32);
      acc = __builtin_amdgcn_mfma_f32_16x16x32_f16(a, b, acc, 0, 0, 0);
    }
    const int n = nt * 16 + rc;
    const int q = l >> 4;
    const int g0 = mt * 16 + q * 4;     // lane's first row
    const float vnf = __shfl(acc[0], (l + 16) & 63, 64);   // next group's acc[0] (valid q<3)
    const __fp16 v0 = (__fp16)acc[0], v1 = (__fp16)acc[1];
    const __fp16 v2 = (__fp16)acc[2], v3 = (__fp16)acc[3];
    __fp16* rowp = ilut + 2 * n;
    // pair stores (row g holds (W[g], W[g+1]))
    if (g0 + 0 < GBIN) *(hp2*)(rowp + (size_t)(g0 + 0) * (2 * NC)) = mkh2(v0, v1);
    if (g0 + 1 < GBIN) *(hp2*)(rowp + (size_t)(g0 + 1) * (2 * NC)) = mkh2(v1, v2);
    if (g0 + 2 < GBIN) *(hp2*)(rowp + (size_t)(g0 + 2) * (2 * NC)) = mkh2(v2, v3);
    if (g0 + 3 < GBIN) {
      if (q < 3) *(hp2*)(rowp + (size_t)(g0 + 3) * (2 * NC)) = mkh2(v3, (__fp16)vnf);
      else        rowp[(size_t)(g0 + 3) * (2 * NC)] = v3;        // lo only; hi by next tile
    }
    if (q == 0 && g0 >= 1 && g0 <= GBIN)                          // hi of previous tile's last row
      rowp[(size_t)(g0 - 1) * (2 * NC) + 1] = v0;
  } else {
    // ---- scan + chunk emission ----
    __shared__ int lds[256];
    const int t = tid;
    int loc[8];
    int s = 0;
#pragma unroll
    for (int i = 0; i < 8; ++i) { loc[i] = cnt[t * 8 + i]; s += loc[i]; }
    lds[t] = s;
    __syncthreads();
    for (int o = 1; o < 256; o <<= 1) {
      int v = 0;
      if (t >= o) v = lds[t - o];
      __syncthreads();
      lds[t] += v;
      __syncthreads();
    }
    int run = lds[t] - s;
    int runs[8];
#pragma unroll
    for (int i = 0; i < 8; ++i) {
      runs[i] = run;
      offs[t * 8 + i] = run;
      woff[t * 8 + i] = run;
      run += loc[i];
    }
    if (t == 255) offs[GBIN] = run;

    int ccnt[8];
    int csum = 0;
#pragma unroll
    for (int i = 0; i < 8; ++i) { ccnt[i] = (loc[i] + 31) >> 5; csum += ccnt[i]; }
    __syncthreads();
    lds[t] = csum;
    __syncthreads();
    for (int o = 1; o < 256; o <<= 1) {
      int v = 0;
      if (t >= o) v = lds[t - o];
      __syncthreads();
      lds[t] += v;
      __syncthreads();
    }
    int crun = lds[t] - csum;
#pragma unroll
    for (int i = 0; i < 8; ++i) {
      for (int c = 0; c < ccnt[i]; ++c) {
        chunk_bin[crun]   = t * 8 + i;
        chunk_start[crun] = runs[i] + c * 32;
        ++crun;
      }
    }
    if (t == 255) nch[0] = lds[255];
  }
}

// ---------------- K3: counting-sort scatter ----------------
__global__ void k_scatter(const int* __restrict__ bin_e, int* __restrict__ woff,
                          int* __restrict__ sorted) {
  const int e = blockIdx.x * 256 + threadIdx.x;
  if (e >= NE) return;
  const int b = bin_e[e];
  if (b >= 0) {
    const int p = atomicAdd(&woff[b], 1);
    sorted[p] = e;
  }
}

// ---------------- K4: epilogue: 32-edge chunk / 128 threads; pair LDS via linear copy ----
__global__ __launch_bounds__(128) void k_epi(
    const __fp16* __restrict__ ilut, const int* __restrict__ chunk_bin,
    const int* __restrict__ chunk_start, const int* __restrict__ offs,
    const int* __restrict__ sorted, const float* __restrict__ f_e,
    const int* __restrict__ ei, const float* __restrict__ pos,
    const float* __restrict__ x, float* __restrict__ out,
    const int* __restrict__ nch) {
  __shared__ __fp16 WP[2 * NC];        // 16640 B
  const int bid = blockIdx.x;
  if (bid >= nch[0]) return;
  const int b     = chunk_bin[bid];
  const int start = chunk_start[bid];
  const int end0  = offs[b + 1];
  const int end   = (start + 32 < end0) ? (start + 32) : end0;
  const int tid = threadIdx.x;
  {  // stage: linear copy of pre-interleaved row (1040 x uint4)
    const uint4* src = (const uint4*)(ilut + (size_t)b * (2 * NC));
    uint4* dst = (uint4*)WP;
    for (int i = tid; i < 1040; i += 128) dst[i] = src[i];
  }
  __syncthreads();
  const int s  = tid & 3;
  const int qb = (tid & 63) & ~3;
  const int slot = start + (tid >> 2);
  if (slot >= end) return;

  const int e = sorted[slot];
  const float f = f_e[e];
  const float fm = 1.f - f;
  const int rec = ei[e], lig = ei[NE + e];
  const float ax = pos[lig * 3 + 0] - pos[rec * 3 + 0];
  const float ay = pos[lig * 3 + 1] - pos[rec * 3 + 1];
  const float az = pos[lig * 3 + 2] - pos[rec * 3 + 2];
  const float d = sqrtf(ax * ax + ay * ay + az * az);
  const float inv = SQ3C / fmaxf(d, 1e-12f);
  const float sh0 = ax * inv, sh1 = ay * inv, sh2 = az * inv;

  // ---- lig features ----
  float s1[16], v1[24];
  {
    const float4* xl = (const float4*)(x + (size_t)lig * 40);
#pragma unroll
    for (int j = 0; j < 4; ++j) {
      float4 v = xl[j];
      s1[j * 4 + 0] = v.x; s1[j * 4 + 1] = v.y; s1[j * 4 + 2] = v.z; s1[j * 4 + 3] = v.w;
    }
#pragma unroll
    for (int j = 0; j < 6; ++j) {
      float4 v = xl[4 + j];
      v1[j * 4 + 0] = v.x; v1[j * 4 + 1] = v.y; v1[j * 4 + 2] = v.z; v1[j * 4 + 3] = v.w;
    }
  }
  float vs[8];
#pragma unroll
  for (int u = 0; u < 8; ++u)
    vs[u] = (v1[u * 3] * sh0 + v1[u * 3 + 1] * sh1 + v1[u * 3 + 2] * sh2) * INV_SQ3;

  // ---- layer 1: sa (lane owns w = 4s..4s+3); lerp folded in fdot2 ----
  float A[4] = {0.f, 0.f, 0.f, 0.f};
#pragma unroll
  for (int u = 0; u < 16; ++u) {   // W000 @ 0
    hp8 w = *(const hp8*)(WP + 2 * (u * 16 + s * 4));
    hp2 sp = pk2(s1[u] * fm, s1[u] * f);
    A[0] = fdot2f(mkh2(w[0], w[1]), sp, A[0]);
    A[1] = fdot2f(mkh2(w[2], w[3]), sp, A[1]);
    A[2] = fdot2f(mkh2(w[4], w[5]), sp, A[2]);
    A[3] = fdot2f(mkh2(w[6], w[7]), sp, A[3]);
  }
#pragma unroll
  for (int u = 0; u < 8; ++u) {    // W110 @ 448
    hp8 w = *(const hp8*)(WP + 2 * (448 + u * 16 + s * 4));
    hp2 sp = pk2(vs[u] * fm, vs[u] * f);
    A[0] = fdot2f(mkh2(w[0], w[1]), sp, A[0]);
    A[1] = fdot2f(mkh2(w[2], w[3]), sp, A[1]);
    A[2] = fdot2f(mkh2(w[4], w[5]), sp, A[2]);
    A[3] = fdot2f(mkh2(w[6], w[7]), sp, A[3]);
  }
  const float sa0 = C0_1F * A[0];
  const float sa1 = C0_1F * A[1];
  const float sa2 = C0_1F * A[2];
  const float sa3 = C0_1F * A[3];

  // ---- layer 1: va (lane owns w = 2s, 2s+1) ----
  float vaA0, vaA1, vaA2, vaB0, vaB1, vaB2;
  {
    float cA = 0.f, cB = 0.f;
#pragma unroll
    for (int u = 0; u < 16; ++u) {  // W011 @ 256
      hp4 w = *(const hp4*)(WP + 2 * (256 + u * 8 + s * 2));
      hp2 sp = pk2(s1[u] * fm, s1[u] * f);
      cA = fdot2f(mkh2(w[0], w[1]), sp, cA);
      cB = fdot2f(mkh2(w[2], w[3]), sp, cB);
    }
    float tAx = 0.f, tAy = 0.f, tAz = 0.f, tBx = 0.f, tBy = 0.f, tBz = 0.f;
#pragma unroll
    for (int u = 0; u < 8; ++u) {   // W101 @ 384
      hp4 w = *(const hp4*)(WP + 2 * (384 + u * 8 + s * 2));
      hp2 px = pk2(v1[u * 3] * fm,     v1[u * 3] * f);
      hp2 py = pk2(v1[u * 3 + 1] * fm, v1[u * 3 + 1] * f);
      hp2 pz = pk2(v1[u * 3 + 2] * fm, v1[u * 3 + 2] * f);
      hp2 pa = mkh2(w[0], w[1]);
      hp2 pb = mkh2(w[2], w[3]);
      tAx = fdot2f(pa, px, tAx); tAy = fdot2f(pa, py, tAy); tAz = fdot2f(pa, pz, tAz);
      tBx = fdot2f(pb, px, tBx); tBy = fdot2f(pb, py, tBy); tBz = fdot2f(pb, pz, tBz);
    }
    vaA0 = C1_1_OS3F * (cA * sh0 + tAx);
    vaA1 = C1_1_OS3F * (cA * sh1 + tAy);
    vaA2 = C1_1_OS3F * (cA * sh2 + tAz);
    vaB0 = C1_1_OS3F * (cB * sh0 + tBx);
    vaB1 = C1_1_OS3F * (cB * sh1 + tBy);
    vaB2 = C1_1_OS3F * (cB * sh2 + tBz);
  }

  // ---- quad allgather ----
  float saF[16];
#pragma unroll
  for (int k = 0; k < 16; ++k) {
    const float v = ((k & 3) == 0) ? sa0 : ((k & 3) == 1) ? sa1 : ((k & 3) == 2) ? sa2 : sa3;
    saF[k] = __shfl(v, qb + (k >> 2), 64);
  }
  float vaF[24];
#pragma unroll
  for (int w = 0; w < 8; ++w) {
    const int src = qb + (w >> 1);
    const float x0 = (w & 1) ? vaB0 : vaA0;
    const float x1 = (w & 1) ? vaB1 : vaA1;
    const float x2 = (w & 1) ? vaB2 : vaA2;
    vaF[w * 3 + 0] = __shfl(x0, src, 64);
    vaF[w * 3 + 1] = __shfl(x1, src, 64);
    vaF[w * 3 + 2] = __shfl(x2, src, 64);
  }

  // ---- rec features: lane's v-subset ----
  const float* xr = x + (size_t)rec * 40;
  const float sbl0 = xr[s],      sbl1 = xr[4 + s];
  const float sbl2 = xr[8 + s],  sbl3 = xr[12 + s];
  const float vbA0 = xr[16 + s * 3 + 0], vbA1 = xr[16 + s * 3 + 1], vbA2 = xr[16 + s * 3 + 2];
  const float vbB0 = xr[16 + (s + 4) * 3 + 0], vbB1 = xr[16 + (s + 4) * 3 + 1], vbB2 = xr[16 + (s + 4) * 3 + 2];

  float oe[20];

  // ===== layer 2: s_out =====
  {
    float so[8];
#pragma unroll
    for (int w = 0; w < 8; ++w) so[w] = 0.f;
#pragma unroll
    for (int u = 0; u < 16; ++u) {   // W000 @ 576: [u:16][v:16][w:8], v = vv*4+s
      const float su = saF[u];
      const __fp16* rp = WP + 2 * (576 + u * 128 + s * 8);
#pragma unroll
      for (int vv = 0; vv < 4; ++vv) {
        const float q = su * ((vv == 0) ? sbl0 : (vv == 1) ? sbl1 : (vv == 2) ? sbl2 : sbl3);
        hp2 qp = pk2(q * fm, q * f);
        hp8 wa = *(const hp8*)(rp + 2 * (vv * 32));
        hp8 wb = *(const hp8*)(rp + 2 * (vv * 32) + 8);
        so[0] = fdot2f(mkh2(wa[0], wa[1]), qp, so[0]);
        so[1] = fdot2f(mkh2(wa[2], wa[3]), qp, so[1]);
        so[2] = fdot2f(mkh2(wa[4], wa[5]), qp, so[2]);
        so[3] = fdot2f(mkh2(wa[6], wa[7]), qp, so[3]);
        so[4] = fdot2f(mkh2(wb[0], wb[1]), qp, so[4]);
        so[5] = fdot2f(mkh2(wb[2], wb[3]), qp, so[5]);
        so[6] = fdot2f(mkh2(wb[4], wb[5]), qp, so[6]);
        so[7] = fdot2f(mkh2(wb[6], wb[7]), qp, so[7]);
      }
    }
#pragma unroll
    for (int u = 0; u < 8; ++u) {    // W110 @ 3648: [u:8][v:8][w:8], v = vv*4+s
      const float a0 = vaF[u * 3], a1 = vaF[u * 3 + 1], a2 = vaF[u * 3 + 2];
      const __fp16* rp = WP + 2 * (3648 + u * 64 + s * 8);
#pragma unroll
      for (int vv = 0; vv < 2; ++vv) {
        const float b0v = vv ? vbB0 : vbA0;
        const float b1v = vv ? vbB1 : vbA1;
        const float b2v = vv ? vbB2 : vbA2;
        const float dd = (a0 * b0v + a1 * b1v + a2 * b2v) * INV_SQ3;
        hp2 qp = pk2(dd * fm, dd * f);
        hp8 wa = *(const hp8*)(rp + 2 * (vv * 32));
        hp8 wb = *(const hp8*)(rp + 2 * (vv * 32) + 8);
        so[0] = fdot2f(mkh2(wa[0], wa[1]), qp, so[0]);
        so[1] = fdot2f(mkh2(wa[2], wa[3]), qp, so[1]);
        so[2] = fdot2f(mkh2(wa[4], wa[5]), qp, so[2]);
        so[3] = fdot2f(mkh2(wa[6], wa[7]), qp, so[3]);
        so[4] = fdot2f(mkh2(wb[0], wb[1]), qp, so[4]);
        so[5] = fdot2f(mkh2(wb[2], wb[3]), qp, so[5]);
        so[6] = fdot2f(mkh2(wb[4], wb[5]), qp, so[6]);
        so[7] = fdot2f(mkh2(wb[6], wb[7]), qp, so[7]);
      }
    }
#pragma unroll
    for (int w = 0; w < 8; ++w) oe[w] = C0_2F * so[w];
  }

  // ===== layer 2: v_out =====
  {
    float uo[12];
#pragma unroll
    for (int w = 0; w < 12; ++w) uo[w] = 0.f;
#pragma unroll
    for (int u = 0; u < 16; ++u) {   // W011 @ 2624: [u:16][v:8][w:4], v = vv*4+s
      const float su = saF[u];
      const __fp16* rp = WP + 2 * (2624 + u * 32 + s * 4);
#pragma unroll
      for (int vv = 0; vv < 2; ++vv) {
        const float q0 = su * (vv ? vbB0 : vbA0);
        const float q1 = su * (vv ? vbB1 : vbA1);
        const float q2 = su * (vv ? vbB2 : vbA2);
        hp2 q0p = pk2(q0 * fm, q0 * f);
        hp2 q1p = pk2(q1 * fm, q1 * f);
        hp2 q2p = pk2(q2 * fm, q2 * f);
        hp8 w = *(const hp8*)(rp + 2 * (vv * 16));
        hp2 p0 = mkh2(w[0], w[1]);
        hp2 p1 = mkh2(w[2], w[3]);
        hp2 p2 = mkh2(w[4], w[5]);
        hp2 p3 = mkh2(w[6], w[7]);
        uo[0] = fdot2f(p0, q0p, uo[0]); uo[1]  = fdot2f(p0, q1p, uo[1]);  uo[2]  = fdot2f(p0, q2p, uo[2]);
        uo[3] = fdot2f(p1, q0p, uo[3]); uo[4]  = fdot2f(p1, q1p, uo[4]);  uo[5]  = fdot2f(p1, q2p, uo[5]);
        uo[6] = fdot2f(p2, q0p, uo[6]); uo[7]  = fdot2f(p2, q1p, uo[7]);  uo[8]  = fdot2f(p2, q2p, uo[8]);
        uo[9] = fdot2f(p3, q0p, uo[9]); uo[10] = fdot2f(p3, q1p, uo[10]); uo[11] = fdot2f(p3, q2p, uo[11]);
      }
    }
#pragma unroll
    for (int u = 0; u < 8; ++u) {    // W101 @ 3136: [u:8][v:16][w:4], v = vv*4+s
      const float a0 = vaF[u * 3], a1 = vaF[u * 3 + 1], a2 = vaF[u * 3 + 2];
      const __fp16* rp = WP + 2 * (3136 + u * 64 + s * 4);
#pragma unroll
      for (int vv = 0; vv < 4; ++vv) {
        const float sbv = (vv == 0) ? sbl0 : (vv == 1) ? sbl1 : (vv == 2) ? sbl2 : sbl3;
        const float q0 = a0 * sbv, q1 = a1 * sbv, q2 = a2 * sbv;
        hp2 q0p = pk2(q0 * fm, q0 * f);
        hp2 q1p = pk2(q1 * fm, q1 * f);
        hp2 q2p = pk2(q2 * fm, q2 * f);
        hp8 w = *(const hp8*)(rp + 2 * (vv * 16));
        hp2 p0 = mkh2(w[0], w[1]);
        hp2 p1 = mkh2(w[2], w[3]);
        hp2 p2 = mkh2(w[4], w[5]);
        hp2 p3 = mkh2(w[6], w[7]);
        uo[0] = fdot2f(p0, q0p, uo[0]); uo[1]  = fdot2f(p0, q1p, uo[1]);  uo[2]  = fdot2f(p0, q2p, uo[2]);
        uo[3] = fdot2f(p1, q0p, uo[3]); uo[4]  = fdot2f(p1, q1p, uo[4]);  uo[5]  = fdot2f(p1, q2p, uo[5]);
        uo[6] = fdot2f(p2, q0p, uo[6]); uo[7]  = fdot2f(p2, q1p, uo[7]);  uo[8]  = fdot2f(p2, q2p, uo[8]);
        uo[9] = fdot2f(p3, q0p, uo[9]); uo[10] = fdot2f(p3, q1p, uo[10]); uo[11] = fdot2f(p3, q2p, uo[11]);
      }
    }
#pragma unroll
    for (int w = 0; w < 12; ++w) oe[8 + w] = C1_2_OS3F * uo[w];
  }

  // ---- quad butterfly reduce + store ----
#pragma unroll
  for (int w = 0; w < 20; ++w) {
    oe[w] += __shfl_xor(oe[w], 1, 64);
    oe[w] += __shfl_xor(oe[w], 2, 64);
  }
  if (s == 0) {
    float4* op = (float4*)(out + (size_t)e * 20);
#pragma unroll
    for (int j = 0; j < 5; ++j) {
      float4 o4;
      o4.x = oe[j * 4 + 0]; o4.y = oe[j * 4 + 1];
      o4.z = oe[j * 4 + 2]; o4.w = oe[j * 4 + 3];
      op[j] = o4;
    }
  }
}

// ---------------- host ----------------
extern "C" void kernel_launch(void* const* d_in, const int* in_sizes, int n_in,
                              void* d_out, int out_size, void* d_ws, size_t ws_size,
                              hipStream_t stream) {
  const int*   ei  = (const int*)d_in[0];
  const float* pos = (const float*)d_in[1];
  const float* x   = (const float*)d_in[2];
  const float* lw1 = (const float*)d_in[3];
  const float* lw2 = (const float*)d_in[4];
  const float* rw1 = (const float*)d_in[5];
  const float* rw2 = (const float*)d_in[6];
  float* out = (float*)d_out;
  char*  ws  = (char*)d_ws;

  size_t o = 0;
  __fp16* ilut = (__fp16*)(ws + o); o += (size_t)GBIN * (2 * NC) * 2;
  o = (o + 15) & ~(size_t)15;
  _Float16* Hl  = (_Float16*)(ws + o); o += (size_t)MPAD * HDIM * 2;
  _Float16* Hr  = (_Float16*)(ws + o); o += (size_t)MPAD * HDIM * 2;
  _Float16* w2t = (_Float16*)(ws + o); o += (size_t)NC * HDIM * 2;
  o = (o + 15) & ~(size_t)15;
  int*   bin_e = (int*)(ws + o);  o += (size_t)NE * 4;
  float* f_e   = (float*)(ws + o); o += (size_t)NE * 4;
  int*   cnt   = (int*)(ws + o);  o += (size_t)GBIN * 4;
  int*   offs  = (int*)(ws + o);  o += (size_t)(GBIN + 1) * 4 + 12;
  int*   woff  = (int*)(ws + o);  o += (size_t)GBIN * 4;
  int*   sorted = (int*)(ws + o); o += (size_t)NE * 4;
  int*   chunk_bin   = (int*)(ws + o); o += (size_t)NCHMAX * 4;
  int*   chunk_start = (int*)(ws + o); o += (size_t)NCHMAX * 4;
  int*   nch = (int*)(ws + o); o += 16;

  // ACT_C on host (runs at capture time, not in the timed graph)
  double ssum = 0.0;
  const double dz = 20.0 / 40000.0;
  for (int i = 0; i <= 40000; ++i) {
    const double z = -10.0 + dz * (double)i;
    const double sil = z / (1.0 + exp(-z));
    const double phi = exp(-0.5 * z * z) / sqrt(2.0 * M_PI);
    ssum += sil * sil * phi;
  }
  const float actc = (float)(1.0 / sqrt(ssum * dz));
  const float k0c  = (float)(1.14136 * exp(2.0));

  hipMemsetAsync(cnt, 0, GBIN * 4, stream);
  k_fused<<<MPAD + NB_W2T + NB_EDGE, 256, 0, stream>>>(
      lw1, rw1, lw2, rw2, actc, k0c, Hl, Hr, w2t, ei, pos, out, bin_e, f_e, cnt);
  k_lutm<<<NB_GEMM + 1, 256, 0, stream>>>(Hl, Hr, w2t, ilut, cnt, offs, woff,
                                          chunk_bin, chunk_start, nch);
  k_scatter<<<(NE + 255) / 256, 256, 0, stream>>>(bin_e, woff, sorted);
  k_epi<<<NCHMAX, 128, 0, stream>>>(ilut, chunk_bin, chunk_start, offs, sorted, f_e,
                                    ei, pos, x, out, nch);
}

// Round 17
// 101.962 us; speedup vs baseline: 1.1712x; 1.0059x over previous
//
#include <hip/hip_runtime.h>
#include <math.h>

#define NE     50000
#define NNODE  10000
#define HDIM   128
#define GBIN   2048
#define NC     4160          // 576 + 3584
#define NC1    576
#define NCHMAX 2830          // 2048 + ceil(50000/64)
#define MPAD   2064          // 129*16 padded grid rows
#define NB_W2T 65            // 65 transpose tiles of 64 columns
#define NB_EDGE 196          // ceil(NE/256)
#define NB_GEMM (129*65)

typedef _Float16 h2 __attribute__((ext_vector_type(2)));
typedef _Float16 h8 __attribute__((ext_vector_type(8)));
typedef float f32x4 __attribute__((ext_vector_type(4)));

typedef __fp16 hp2 __attribute__((ext_vector_type(2)));
typedef __fp16 hp4 __attribute__((ext_vector_type(4)));
typedef __fp16 hp8 __attribute__((ext_vector_type(8)));

static __device__ __forceinline__ float fdot2f(hp2 p, hp2 q, float acc) {
  return __builtin_amdgcn_fdot2(p, q, acc, false);
}
static __device__ __forceinline__ hp2 pk2(float a, float b) {
  hp2 r = __builtin_amdgcn_cvt_pkrtz(a, b);
  return r;
}
static __device__ __forceinline__ hp2 mkh2(__fp16 a, __fp16 b) {
  hp2 o; o[0] = a; o[1] = b;
  return o;
}

// constants
#define SQ3C        1.7320508075688772f
#define INV_SQ3     0.5773502691896258f
#define C0_1F       0.20412414523193154f   // 1/sqrt(24)
#define C1_1_OS3F   0.20412414523193154f   // sqrt(3/24)/sqrt(3)
#define C0_2F       0.05590169943749474f   // 1/sqrt(320)
#define C1_2_OS3F   0.0625f                // sqrt(3/256)/sqrt(3)
#define INV_SQRT_H  0.08838834764831845f   // 1/sqrt(128)
#define DELTA       (5.0f/2048.0f)
#define INV_DELTA   409.6f
#define STEP_INV    (51.0f/5.0f)

// ---------------- K1: fused prologue ----------------
__global__ __launch_bounds__(256) void k_fused(
    const float* __restrict__ lw1, const float* __restrict__ rw1,
    const float* __restrict__ lw2, const float* __restrict__ rw2,
    const float actc, const float K0C,
    _Float16* __restrict__ Hl, _Float16* __restrict__ Hr,
    _Float16* __restrict__ w2t,
    const int* __restrict__ ei, const float* __restrict__ pos,
    float* __restrict__ out, int* __restrict__ bin_e,
    float* __restrict__ f_e, int* __restrict__ cnt) {
  __shared__ _Float16 TT[64 * 136];   // 17408 B (transpose tile)
  const int bid = blockIdx.x;
  const int tid = threadIdx.x;
  if (bid < MPAD) {
    const int g = bid;
    const int which = tid >> 7, hc = tid & 127;
    const float* __restrict__ w1 = which ? rw1 : lw1;
    float h = 0.f;
    if (g <= GBIN) {
      const float tt = (float)g * DELTA * STEP_INV;
      const int i0 = (int)floorf(tt);
      float z = 0.f;
#pragma unroll
      for (int k = 0; k < 2; ++k) {
        const int ii = i0 + k;
        if (ii >= 1 && ii <= 50) {
          const float diff = tt - (float)ii;
          const float a = diff + 1.f, b = 1.f - diff;
          if (a > 0.f && b > 0.f) {
            const float val = K0C * __expf(-1.f / a - 1.f / b);
            z += val * w1[(ii - 1) * HDIM + hc];
          }
        }
      }
      h = actc * z / (1.f + __expf(-z)) * INV_SQRT_H;
    }
    _Float16* __restrict__ H = which ? Hr : Hl;
    H[(size_t)g * HDIM + hc] = (_Float16)h;
  } else if (bid < MPAD + NB_W2T) {
    const int b = bid - MPAD;
    const int n0 = b * 64;
    const int isrec = (n0 >= NC1);
    const float* __restrict__ src = isrec ? rw2 : lw2;
    const int ncols = isrec ? 3584 : NC1;
    const int c0 = isrec ? (n0 - NC1) : n0;
#pragma unroll
    for (int i = 0; i < 32; ++i) {
      const int idx = i * 256 + tid;
      const int k = idx >> 6;
      const int j = idx & 63;
      TT[j * 136 + k] = (_Float16)src[(size_t)k * ncols + c0 + j];
    }
    __syncthreads();
#pragma unroll
    for (int it = 0; it < 4; ++it) {
      const int jj = it * 16 + (tid >> 4);
      const int kc = tid & 15;
      h8 w = *(const h8*)&TT[jj * 136 + kc * 8];
      *(h8*)(w2t + (size_t)(n0 + jj) * HDIM + kc * 8) = w;
    }
  } else {
    const int e = (bid - MPAD - NB_W2T) * 256 + tid;
    if (e >= NE) return;
    const int rec = ei[e], lig = ei[NE + e];
    const float ax = pos[lig * 3 + 0] - pos[rec * 3 + 0];
    const float ay = pos[lig * 3 + 1] - pos[rec * 3 + 1];
    const float az = pos[lig * 3 + 2] - pos[rec * 3 + 2];
    const float d = sqrtf(ax * ax + ay * ay + az * az);
    if (d > 0.f && d < 5.0f) {
      const float tf = d * INV_DELTA;
      int b = (int)tf;
      if (b > GBIN - 1) b = GBIN - 1;
      bin_e[e] = b;
      f_e[e] = tf - (float)b;
      atomicAdd(&cnt[b], 1);
    } else {
      bin_e[e] = -1;
      float* o = out + (size_t)e * 20;
#pragma unroll
      for (int i2 = 0; i2 < 20; ++i2) o[i2] = 0.f;
    }
  }
}

// ---------------- K2: LUT GEMM (pair-interleaved output, 4B pair stores) + scan ----------
__global__ __launch_bounds__(256) void k_lutm(
    const _Float16* __restrict__ Hl, const _Float16* __restrict__ Hr,
    const _Float16* __restrict__ w2t, __fp16* __restrict__ ilut,
    const int* __restrict__ cnt, int* __restrict__ offs,
    int* __restrict__ woff, int* __restrict__ chunk_bin,
    int* __restrict__ chunk_start, int* __restrict__ nch) {
  const int bid = blockIdx.x;
  const int tid = threadIdx.x;
  if (bid < NB_GEMM) {
    const int mt = bid % 129;
    const int nt = (bid / 129) * 4 + (tid >> 6);   // 0..259
    const int l  = tid & 63;
    const int rc = l & 15;
    const int kg = (l >> 4) * 8;
    const _Float16* __restrict__ Ap =
        ((nt < 36) ? Hl : Hr) + (size_t)(mt * 16 + rc) * HDIM + kg;
    const _Float16* __restrict__ Bp = w2t + (size_t)(nt * 16 + rc) * HDIM + kg;
    f32x4 acc = {0.f, 0.f, 0.f, 0.f};
#pragma unroll
    for (int kc = 0; kc < 4; ++kc) {
      h8 a = *(const h8*)(Ap + kc * 32);
      h8 b = *(const h8*)(Bp + kc * 32);
      acc = __builtin_amdgcn_mfma_f32_16x16x32_f16(a, b, acc, 0, 0, 0);
    }
    const int n = nt * 16 + rc;
    const int q = l >> 4;
    const int g0 = mt * 16 + q * 4;
    const float vnf = __shfl(acc[0], (l + 16) & 63, 64);
    const __fp16 v0 = (__fp16)acc[0], v1 = (__fp16)acc[1];
    const __fp16 v2 = (__fp16)acc[2], v3 = (__fp16)acc[3];
    __fp16* rowp = ilut + 2 * n;
    if (g0 + 0 < GBIN) *(hp2*)(rowp + (size_t)(g0 + 0) * (2 * NC)) = mkh2(v0, v1);
    if (g0 + 1 < GBIN) *(hp2*)(rowp + (size_t)(g0 + 1) * (2 * NC)) = mkh2(v1, v2);
    if (g0 + 2 < GBIN) *(hp2*)(rowp + (size_t)(g0 + 2) * (2 * NC)) = mkh2(v2, v3);
    if (g0 + 3 < GBIN) {
      if (q < 3) *(hp2*)(rowp + (size_t)(g0 + 3) * (2 * NC)) = mkh2(v3, (__fp16)vnf);
      else        rowp[(size_t)(g0 + 3) * (2 * NC)] = v3;
    }
    if (q == 0 && g0 >= 1 && g0 <= GBIN)
      rowp[(size_t)(g0 - 1) * (2 * NC) + 1] = v0;
  } else {
    __shared__ int lds[256];
    const int t = tid;
    int loc[8];
    int s = 0;
#pragma unroll
    for (int i = 0; i < 8; ++i) { loc[i] = cnt[t * 8 + i]; s += loc[i]; }
    lds[t] = s;
    __syncthreads();
    for (int o = 1; o < 256; o <<= 1) {
      int v = 0;
      if (t >= o) v = lds[t - o];
      __syncthreads();
      lds[t] += v;
      __syncthreads();
    }
    int run = lds[t] - s;
    int runs[8];
#pragma unroll
    for (int i = 0; i < 8; ++i) {
      runs[i] = run;
      offs[t * 8 + i] = run;
      woff[t * 8 + i] = run;
      run += loc[i];
    }
    if (t == 255) offs[GBIN] = run;

    int ccnt[8];
    int csum = 0;
#pragma unroll
    for (int i = 0; i < 8; ++i) { ccnt[i] = (loc[i] + 63) >> 6; csum += ccnt[i]; }
    __syncthreads();
    lds[t] = csum;
    __syncthreads();
    for (int o = 1; o < 256; o <<= 1) {
      int v = 0;
      if (t >= o) v = lds[t - o];
      __syncthreads();
      lds[t] += v;
      __syncthreads();
    }
    int crun = lds[t] - csum;
#pragma unroll
    for (int i = 0; i < 8; ++i) {
      for (int c = 0; c < ccnt[i]; ++c) {
        chunk_bin[crun]   = t * 8 + i;
        chunk_start[crun] = runs[i] + c * 64;
        ++crun;
      }
    }
    if (t == 255) nch[0] = lds[255];
  }
}

// ---------------- K3: counting-sort scatter ----------------
__global__ void k_scatter(const int* __restrict__ bin_e, int* __restrict__ woff,
                          int* __restrict__ sorted) {
  const int e = blockIdx.x * 256 + threadIdx.x;
  if (e >= NE) return;
  const int b = bin_e[e];
  if (b >= 0) {
    const int p = atomicAdd(&woff[b], 1);
    sorted[p] = e;
  }
}

// ---------------- K4: epilogue: 64-edge chunk / 256 threads; pair LDS via linear copy ----
__global__ __launch_bounds__(256) void k_epi(
    const __fp16* __restrict__ ilut, const int* __restrict__ chunk_bin,
    const int* __restrict__ chunk_start, const int* __restrict__ offs,
    const int* __restrict__ sorted, const float* __restrict__ f_e,
    const int* __restrict__ ei, const float* __restrict__ pos,
    const float* __restrict__ x, float* __restrict__ out,
    const int* __restrict__ nch) {
  __shared__ __fp16 WP[2 * NC];        // 16640 B
  const int bid = blockIdx.x;
  if (bid >= nch[0]) return;
  const int b     = chunk_bin[bid];
  const int start = chunk_start[bid];
  const int end0  = offs[b + 1];
  const int end   = (start + 64 < end0) ? (start + 64) : end0;
  const int tid = threadIdx.x;
  {  // stage: linear copy of pre-interleaved row (1040 x uint4)
    const uint4* src = (const uint4*)(ilut + (size_t)b * (2 * NC));
    uint4* dst = (uint4*)WP;
    for (int i = tid; i < 1040; i += 256) dst[i] = src[i];
  }
  __syncthreads();
  const int s  = tid & 3;
  const int qb = (tid & 63) & ~3;
  const int slot = start + (tid >> 2);
  if (slot >= end) return;

  const int e = sorted[slot];
  const float f = f_e[e];
  const float fm = 1.f - f;
  const int rec = ei[e], lig = ei[NE + e];
  const float ax = pos[lig * 3 + 0] - pos[rec * 3 + 0];
  const float ay = pos[lig * 3 + 1] - pos[rec * 3 + 1];
  const float az = pos[lig * 3 + 2] - pos[rec * 3 + 2];
  const float d = sqrtf(ax * ax + ay * ay + az * az);
  const float inv = SQ3C / fmaxf(d, 1e-12f);
  const float sh0 = ax * inv, sh1 = ay * inv, sh2 = az * inv;

  // ---- lig features ----
  float s1[16], v1[24];
  {
    const float4* xl = (const float4*)(x + (size_t)lig * 40);
#pragma unroll
    for (int j = 0; j < 4; ++j) {
      float4 v = xl[j];
      s1[j * 4 + 0] = v.x; s1[j * 4 + 1] = v.y; s1[j * 4 + 2] = v.z; s1[j * 4 + 3] = v.w;
    }
#pragma unroll
    for (int j = 0; j < 6; ++j) {
      float4 v = xl[4 + j];
      v1[j * 4 + 0] = v.x; v1[j * 4 + 1] = v.y; v1[j * 4 + 2] = v.z; v1[j * 4 + 3] = v.w;
    }
  }
  float vs[8];
#pragma unroll
  for (int u = 0; u < 8; ++u)
    vs[u] = (v1[u * 3] * sh0 + v1[u * 3 + 1] * sh1 + v1[u * 3 + 2] * sh2) * INV_SQ3;

  // ---- layer 1: sa (lane owns w = 4s..4s+3); lerp folded in fdot2 ----
  float A[4] = {0.f, 0.f, 0.f, 0.f};
#pragma unroll
  for (int u = 0; u < 16; ++u) {   // W000 @ 0
    hp8 w = *(const hp8*)(WP + 2 * (u * 16 + s * 4));
    hp2 sp = pk2(s1[u] * fm, s1[u] * f);
    A[0] = fdot2f(mkh2(w[0], w[1]), sp, A[0]);
    A[1] = fdot2f(mkh2(w[2], w[3]), sp, A[1]);
    A[2] = fdot2f(mkh2(w[4], w[5]), sp, A[2]);
    A[3] = fdot2f(mkh2(w[6], w[7]), sp, A[3]);
  }
#pragma unroll
  for (int u = 0; u < 8; ++u) {    // W110 @ 448
    hp8 w = *(const hp8*)(WP + 2 * (448 + u * 16 + s * 4));
    hp2 sp = pk2(vs[u] * fm, vs[u] * f);
    A[0] = fdot2f(mkh2(w[0], w[1]), sp, A[0]);
    A[1] = fdot2f(mkh2(w[2], w[3]), sp, A[1]);
    A[2] = fdot2f(mkh2(w[4], w[5]), sp, A[2]);
    A[3] = fdot2f(mkh2(w[6], w[7]), sp, A[3]);
  }
  const float sa0 = C0_1F * A[0];
  const float sa1 = C0_1F * A[1];
  const float sa2 = C0_1F * A[2];
  const float sa3 = C0_1F * A[3];

  // ---- layer 1: va (lane owns w = 2s, 2s+1) ----
  float vaA0, vaA1, vaA2, vaB0, vaB1, vaB2;
  {
    float cA = 0.f, cB = 0.f;
#pragma unroll
    for (int u = 0; u < 16; ++u) {  // W011 @ 256
      hp4 w = *(const hp4*)(WP + 2 * (256 + u * 8 + s * 2));
      hp2 sp = pk2(s1[u] * fm, s1[u] * f);
      cA = fdot2f(mkh2(w[0], w[1]), sp, cA);
      cB = fdot2f(mkh2(w[2], w[3]), sp, cB);
    }
    float tAx = 0.f, tAy = 0.f, tAz = 0.f, tBx = 0.f, tBy = 0.f, tBz = 0.f;
#pragma unroll
    for (int u = 0; u < 8; ++u) {   // W101 @ 384
      hp4 w = *(const hp4*)(WP + 2 * (384 + u * 8 + s * 2));
      hp2 px = pk2(v1[u * 3] * fm,     v1[u * 3] * f);
      hp2 py = pk2(v1[u * 3 + 1] * fm, v1[u * 3 + 1] * f);
      hp2 pz = pk2(v1[u * 3 + 2] * fm, v1[u * 3 + 2] * f);
      hp2 pa = mkh2(w[0], w[1]);
      hp2 pb = mkh2(w[2], w[3]);
      tAx = fdot2f(pa, px, tAx); tAy = fdot2f(pa, py, tAy); tAz = fdot2f(pa, pz, tAz);
      tBx = fdot2f(pb, px, tBx); tBy = fdot2f(pb, py, tBy); tBz = fdot2f(pb, pz, tBz);
    }
    vaA0 = C1_1_OS3F * (cA * sh0 + tAx);
    vaA1 = C1_1_OS3F * (cA * sh1 + tAy);
    vaA2 = C1_1_OS3F * (cA * sh2 + tAz);
    vaB0 = C1_1_OS3F * (cB * sh0 + tBx);
    vaB1 = C1_1_OS3F * (cB * sh1 + tBy);
    vaB2 = C1_1_OS3F * (cB * sh2 + tBz);
  }

  // ---- quad allgather (within wave) ----
  float saF[16];
#pragma unroll
  for (int k = 0; k < 16; ++k) {
    const float v = ((k & 3) == 0) ? sa0 : ((k & 3) == 1) ? sa1 : ((k & 3) == 2) ? sa2 : sa3;
    saF[k] = __shfl(v, qb + (k >> 2), 64);
  }
  float vaF[24];
#pragma unroll
  for (int w = 0; w < 8; ++w) {
    const int src = qb + (w >> 1);
    const float x0 = (w & 1) ? vaB0 : vaA0;
    const float x1 = (w & 1) ? vaB1 : vaA1;
    const float x2 = (w & 1) ? vaB2 : vaA2;
    vaF[w * 3 + 0] = __shfl(x0, src, 64);
    vaF[w * 3 + 1] = __shfl(x1, src, 64);
    vaF[w * 3 + 2] = __shfl(x2, src, 64);
  }

  // ---- rec features: lane's v-subset ----
  const float* xr = x + (size_t)rec * 40;
  const float sbl0 = xr[s],      sbl1 = xr[4 + s];
  const float sbl2 = xr[8 + s],  sbl3 = xr[12 + s];
  const float vbA0 = xr[16 + s * 3 + 0], vbA1 = xr[16 + s * 3 + 1], vbA2 = xr[16 + s * 3 + 2];
  const float vbB0 = xr[16 + (s + 4) * 3 + 0], vbB1 = xr[16 + (s + 4) * 3 + 1], vbB2 = xr[16 + (s + 4) * 3 + 2];

  float oe[20];

  // ===== layer 2: s_out =====
  {
    float so[8];
#pragma unroll
    for (int w = 0; w < 8; ++w) so[w] = 0.f;
#pragma unroll
    for (int u = 0; u < 16; ++u) {   // W000 @ 576: [u:16][v:16][w:8], v = vv*4+s
      const float su = saF[u];
      const __fp16* rp = WP + 2 * (576 + u * 128 + s * 8);
#pragma unroll
      for (int vv = 0; vv < 4; ++vv) {
        const float q = su * ((vv == 0) ? sbl0 : (vv == 1) ? sbl1 : (vv == 2) ? sbl2 : sbl3);
        hp2 qp = pk2(q * fm, q * f);
        hp8 wa = *(const hp8*)(rp + 2 * (vv * 32));
        hp8 wb = *(const hp8*)(rp + 2 * (vv * 32) + 8);
        so[0] = fdot2f(mkh2(wa[0], wa[1]), qp, so[0]);
        so[1] = fdot2f(mkh2(wa[2], wa[3]), qp, so[1]);
        so[2] = fdot2f(mkh2(wa[4], wa[5]), qp, so[2]);
        so[3] = fdot2f(mkh2(wa[6], wa[7]), qp, so[3]);
        so[4] = fdot2f(mkh2(wb[0], wb[1]), qp, so[4]);
        so[5] = fdot2f(mkh2(wb[2], wb[3]), qp, so[5]);
        so[6] = fdot2f(mkh2(wb[4], wb[5]), qp, so[6]);
        so[7] = fdot2f(mkh2(wb[6], wb[7]), qp, so[7]);
      }
    }
#pragma unroll
    for (int u = 0; u < 8; ++u) {    // W110 @ 3648: [u:8][v:8][w:8], v = vv*4+s
      const float a0 = vaF[u * 3], a1 = vaF[u * 3 + 1], a2 = vaF[u * 3 + 2];
      const __fp16* rp = WP + 2 * (3648 + u * 64 + s * 8);
#pragma unroll
      for (int vv = 0; vv < 2; ++vv) {
        const float b0v = vv ? vbB0 : vbA0;
        const float b1v = vv ? vbB1 : vbA1;
        const float b2v = vv ? vbB2 : vbA2;
        const float dd = (a0 * b0v + a1 * b1v + a2 * b2v) * INV_SQ3;
        hp2 qp = pk2(dd * fm, dd * f);
        hp8 wa = *(const hp8*)(rp + 2 * (vv * 32));
        hp8 wb = *(const hp8*)(rp + 2 * (vv * 32) + 8);
        so[0] = fdot2f(mkh2(wa[0], wa[1]), qp, so[0]);
        so[1] = fdot2f(mkh2(wa[2], wa[3]), qp, so[1]);
        so[2] = fdot2f(mkh2(wa[4], wa[5]), qp, so[2]);
        so[3] = fdot2f(mkh2(wa[6], wa[7]), qp, so[3]);
        so[4] = fdot2f(mkh2(wb[0], wb[1]), qp, so[4]);
        so[5] = fdot2f(mkh2(wb[2], wb[3]), qp, so[5]);
        so[6] = fdot2f(mkh2(wb[4], wb[5]), qp, so[6]);
        so[7] = fdot2f(mkh2(wb[6], wb[7]), qp, so[7]);
      }
    }
#pragma unroll
    for (int w = 0; w < 8; ++w) oe[w] = C0_2F * so[w];
  }

  // ===== layer 2: v_out =====
  {
    float uo[12];
#pragma unroll
    for (int w = 0; w < 12; ++w) uo[w] = 0.f;
#pragma unroll
    for (int u = 0; u < 16; ++u) {   // W011 @ 2624: [u:16][v:8][w:4], v = vv*4+s
      const float su = saF[u];
      const __fp16* rp = WP + 2 * (2624 + u * 32 + s * 4);
#pragma unroll
      for (int vv = 0; vv < 2; ++vv) {
        const float q0 = su * (vv ? vbB0 : vbA0);
        const float q1 = su * (vv ? vbB1 : vbA1);
        const float q2 = su * (vv ? vbB2 : vbA2);
        hp2 q0p = pk2(q0 * fm, q0 * f);
        hp2 q1p = pk2(q1 * fm, q1 * f);
        hp2 q2p = pk2(q2 * fm, q2 * f);
        hp8 w = *(const hp8*)(rp + 2 * (vv * 16));
        hp2 p0 = mkh2(w[0], w[1]);
        hp2 p1 = mkh2(w[2], w[3]);
        hp2 p2 = mkh2(w[4], w[5]);
        hp2 p3 = mkh2(w[6], w[7]);
        uo[0] = fdot2f(p0, q0p, uo[0]); uo[1]  = fdot2f(p0, q1p, uo[1]);  uo[2]  = fdot2f(p0, q2p, uo[2]);
        uo[3] = fdot2f(p1, q0p, uo[3]); uo[4]  = fdot2f(p1, q1p, uo[4]);  uo[5]  = fdot2f(p1, q2p, uo[5]);
        uo[6] = fdot2f(p2, q0p, uo[6]); uo[7]  = fdot2f(p2, q1p, uo[7]);  uo[8]  = fdot2f(p2, q2p, uo[8]);
        uo[9] = fdot2f(p3, q0p, uo[9]); uo[10] = fdot2f(p3, q1p, uo[10]); uo[11] = fdot2f(p3, q2p, uo[11]);
      }
    }
#pragma unroll
    for (int u = 0; u < 8; ++u) {    // W101 @ 3136: [u:8][v:16][w:4], v = vv*4+s
      const float a0 = vaF[u * 3], a1 = vaF[u * 3 + 1], a2 = vaF[u * 3 + 2];
      const __fp16* rp = WP + 2 * (3136 + u * 64 + s * 4);
#pragma unroll
      for (int vv = 0; vv < 4; ++vv) {
        const float sbv = (vv == 0) ? sbl0 : (vv == 1) ? sbl1 : (vv == 2) ? sbl2 : sbl3;
        const float q0 = a0 * sbv, q1 = a1 * sbv, q2 = a2 * sbv;
        hp2 q0p = pk2(q0 * fm, q0 * f);
        hp2 q1p = pk2(q1 * fm, q1 * f);
        hp2 q2p = pk2(q2 * fm, q2 * f);
        hp8 w = *(const hp8*)(rp + 2 * (vv * 16));
        hp2 p0 = mkh2(w[0], w[1]);
        hp2 p1 = mkh2(w[2], w[3]);
        hp2 p2 = mkh2(w[4], w[5]);
        hp2 p3 = mkh2(w[6], w[7]);
        uo[0] = fdot2f(p0, q0p, uo[0]); uo[1]  = fdot2f(p0, q1p, uo[1]);  uo[2]  = fdot2f(p0, q2p, uo[2]);
        uo[3] = fdot2f(p1, q0p, uo[3]); uo[4]  = fdot2f(p1, q1p, uo[4]);  uo[5]  = fdot2f(p1, q2p, uo[5]);
        uo[6] = fdot2f(p2, q0p, uo[6]); uo[7]  = fdot2f(p2, q1p, uo[7]);  uo[8]  = fdot2f(p2, q2p, uo[8]);
        uo[9] = fdot2f(p3, q0p, uo[9]); uo[10] = fdot2f(p3, q1p, uo[10]); uo[11] = fdot2f(p3, q2p, uo[11]);
      }
    }
#pragma unroll
    for (int w = 0; w < 12; ++w) oe[8 + w] = C1_2_OS3F * uo[w];
  }

  // ---- quad butterfly reduce + store ----
#pragma unroll
  for (int w = 0; w < 20; ++w) {
    oe[w] += __shfl_xor(oe[w], 1, 64);
    oe[w] += __shfl_xor(oe[w], 2, 64);
  }
  if (s == 0) {
    float4* op = (float4*)(out + (size_t)e * 20);
#pragma unroll
    for (int j = 0; j < 5; ++j) {
      float4 o4;
      o4.x = oe[j * 4 + 0]; o4.y = oe[j * 4 + 1];
      o4.z = oe[j * 4 + 2]; o4.w = oe[j * 4 + 3];
      op[j] = o4;
    }
  }
}

// ---------------- host ----------------
extern "C" void kernel_launch(void* const* d_in, const int* in_sizes, int n_in,
                              void* d_out, int out_size, void* d_ws, size_t ws_size,
                              hipStream_t stream) {
  const int*   ei  = (const int*)d_in[0];
  const float* pos = (const float*)d_in[1];
  const float* x   = (const float*)d_in[2];
  const float* lw1 = (const float*)d_in[3];
  const float* lw2 = (const float*)d_in[4];
  const float* rw1 = (const float*)d_in[5];
  const float* rw2 = (const float*)d_in[6];
  float* out = (float*)d_out;
  char*  ws  = (char*)d_ws;

  size_t o = 0;
  __fp16* ilut = (__fp16*)(ws + o); o += (size_t)GBIN * (2 * NC) * 2;
  o = (o + 15) & ~(size_t)15;
  _Float16* Hl  = (_Float16*)(ws + o); o += (size_t)MPAD * HDIM * 2;
  _Float16* Hr  = (_Float16*)(ws + o); o += (size_t)MPAD * HDIM * 2;
  _Float16* w2t = (_Float16*)(ws + o); o += (size_t)NC * HDIM * 2;
  o = (o + 15) & ~(size_t)15;
  int*   bin_e = (int*)(ws + o);  o += (size_t)NE * 4;
  float* f_e   = (float*)(ws + o); o += (size_t)NE * 4;
  int*   cnt   = (int*)(ws + o);  o += (size_t)GBIN * 4;
  int*   offs  = (int*)(ws + o);  o += (size_t)(GBIN + 1) * 4 + 12;
  int*   woff  = (int*)(ws + o);  o += (size_t)GBIN * 4;
  int*   sorted = (int*)(ws + o); o += (size_t)NE * 4;
  int*   chunk_bin   = (int*)(ws + o); o += (size_t)NCHMAX * 4;
  int*   chunk_start = (int*)(ws + o); o += (size_t)NCHMAX * 4;
  int*   nch = (int*)(ws + o); o += 16;

  // ACT_C on host (runs at capture time, not in the timed graph)
  double ssum = 0.0;
  const double dz = 20.0 / 40000.0;
  for (int i = 0; i <= 40000; ++i) {
    const double z = -10.0 + dz * (double)i;
    const double sil = z / (1.0 + exp(-z));
    const double phi = exp(-0.5 * z * z) / sqrt(2.0 * M_PI);
    ssum += sil * sil * phi;
  }
  const float actc = (float)(1.0 / sqrt(ssum * dz));
  const float k0c  = (float)(1.14136 * exp(2.0));

  hipMemsetAsync(cnt, 0, GBIN * 4, stream);
  k_fused<<<MPAD + NB_W2T + NB_EDGE, 256, 0, stream>>>(
      lw1, rw1, lw2, rw2, actc, k0c, Hl, Hr, w2t, ei, pos, out, bin_e, f_e, cnt);
  k_lutm<<<NB_GEMM + 1, 256, 0, stream>>>(Hl, Hr, w2t, ilut, cnt, offs, woff,
                                          chunk_bin, chunk_start, nch);
  k_scatter<<<(NE + 255) / 256, 256, 0, stream>>>(bin_e, woff, sorted);
  k_epi<<<NCHMAX, 256, 0, stream>>>(ilut, chunk_bin, chunk_start, offs, sorted, f_e,
                                    ei, pos, x, out, nch);
}

// Round 18
// 100.850 us; speedup vs baseline: 1.1841x; 1.0110x over previous
//
#include <hip/hip_runtime.h>
#include <math.h>

#define NE     50000
#define NNODE  10000
#define HDIM   128
#define GBIN   2048
#define NC     4160          // 576 + 3584
#define NC1    576
#define NCHMAX 1900          // 1024 pairs + ceil(50000/64)
#define MPAD   2064          // 129*16 padded grid rows
#define NB_W2T 65            // 65 transpose tiles of 64 columns
#define NB_EDGE 196          // ceil(NE/256)
#define NB_GEMM (129*65)

typedef _Float16 h2 __attribute__((ext_vector_type(2)));
typedef _Float16 h8 __attribute__((ext_vector_type(8)));
typedef float f32x4 __attribute__((ext_vector_type(4)));

typedef __fp16 hp2 __attribute__((ext_vector_type(2)));
typedef __fp16 hp4 __attribute__((ext_vector_type(4)));
typedef __fp16 hp8 __attribute__((ext_vector_type(8)));

static __device__ __forceinline__ float fdot2f(hp2 p, hp2 q, float acc) {
  return __builtin_amdgcn_fdot2(p, q, acc, false);
}
static __device__ __forceinline__ hp2 pk2(float a, float b) {
  hp2 r = __builtin_amdgcn_cvt_pkrtz(a, b);
  return r;
}
static __device__ __forceinline__ hp2 mkh2(__fp16 a, __fp16 b) {
  hp2 o; o[0] = a; o[1] = b;
  return o;
}

// constants
#define SQ3C        1.7320508075688772f
#define INV_SQ3     0.5773502691896258f
#define C0_1F       0.20412414523193154f   // 1/sqrt(24)
#define C1_1_OS3F   0.20412414523193154f   // sqrt(3/24)/sqrt(3)
#define C0_2F       0.05590169943749474f   // 1/sqrt(320)
#define C1_2_OS3F   0.0625f                // sqrt(3/256)/sqrt(3)
#define INV_SQRT_H  0.08838834764831845f   // 1/sqrt(128)
#define DELTA       (5.0f/2048.0f)
#define INV_DELTA   409.6f
#define STEP_INV    (51.0f/5.0f)

// ---------------- K1: fused prologue ----------------
__global__ __launch_bounds__(256) void k_fused(
    const float* __restrict__ lw1, const float* __restrict__ rw1,
    const float* __restrict__ lw2, const float* __restrict__ rw2,
    const float actc, const float K0C,
    _Float16* __restrict__ Hl, _Float16* __restrict__ Hr,
    _Float16* __restrict__ w2t,
    const int* __restrict__ ei, const float* __restrict__ pos,
    float* __restrict__ out, int* __restrict__ bin_e,
    float* __restrict__ f_e, int* __restrict__ cnt) {
  __shared__ _Float16 TT[64 * 136];   // 17408 B (transpose tile)
  const int bid = blockIdx.x;
  const int tid = threadIdx.x;
  if (bid < MPAD) {
    const int g = bid;
    const int which = tid >> 7, hc = tid & 127;
    const float* __restrict__ w1 = which ? rw1 : lw1;
    float h = 0.f;
    if (g <= GBIN) {
      const float tt = (float)g * DELTA * STEP_INV;
      const int i0 = (int)floorf(tt);
      float z = 0.f;
#pragma unroll
      for (int k = 0; k < 2; ++k) {
        const int ii = i0 + k;
        if (ii >= 1 && ii <= 50) {
          const float diff = tt - (float)ii;
          const float a = diff + 1.f, b = 1.f - diff;
          if (a > 0.f && b > 0.f) {
            const float val = K0C * __expf(-1.f / a - 1.f / b);
            z += val * w1[(ii - 1) * HDIM + hc];
          }
        }
      }
      h = actc * z / (1.f + __expf(-z)) * INV_SQRT_H;
    }
    _Float16* __restrict__ H = which ? Hr : Hl;
    H[(size_t)g * HDIM + hc] = (_Float16)h;
  } else if (bid < MPAD + NB_W2T) {
    const int b = bid - MPAD;
    const int n0 = b * 64;
    const int isrec = (n0 >= NC1);
    const float* __restrict__ src = isrec ? rw2 : lw2;
    const int ncols = isrec ? 3584 : NC1;
    const int c0 = isrec ? (n0 - NC1) : n0;
#pragma unroll
    for (int i = 0; i < 32; ++i) {
      const int idx = i * 256 + tid;
      const int k = idx >> 6;
      const int j = idx & 63;
      TT[j * 136 + k] = (_Float16)src[(size_t)k * ncols + c0 + j];
    }
    __syncthreads();
#pragma unroll
    for (int it = 0; it < 4; ++it) {
      const int jj = it * 16 + (tid >> 4);
      const int kc = tid & 15;
      h8 w = *(const h8*)&TT[jj * 136 + kc * 8];
      *(h8*)(w2t + (size_t)(n0 + jj) * HDIM + kc * 8) = w;
    }
  } else {
    const int e = (bid - MPAD - NB_W2T) * 256 + tid;
    if (e >= NE) return;
    const int rec = ei[e], lig = ei[NE + e];
    const float ax = pos[lig * 3 + 0] - pos[rec * 3 + 0];
    const float ay = pos[lig * 3 + 1] - pos[rec * 3 + 1];
    const float az = pos[lig * 3 + 2] - pos[rec * 3 + 2];
    const float d = sqrtf(ax * ax + ay * ay + az * az);
    if (d > 0.f && d < 5.0f) {
      const float tf = d * INV_DELTA;
      int b = (int)tf;
      if (b > GBIN - 1) b = GBIN - 1;
      bin_e[e] = b;
      f_e[e] = tf - (float)b;
      atomicAdd(&cnt[b], 1);
    } else {
      bin_e[e] = -1;
      float* o = out + (size_t)e * 20;
#pragma unroll
      for (int i2 = 0; i2 < 20; ++i2) o[i2] = 0.f;
    }
  }
}

// ---------------- K2: LUT GEMM (pair-interleaved output) + pair-chunk scan ----------
__global__ __launch_bounds__(256) void k_lutm(
    const _Float16* __restrict__ Hl, const _Float16* __restrict__ Hr,
    const _Float16* __restrict__ w2t, __fp16* __restrict__ ilut,
    const int* __restrict__ cnt, int* __restrict__ offs,
    int* __restrict__ woff, int* __restrict__ chunk_pair,
    int* __restrict__ chunk_start, int* __restrict__ nch) {
  const int bid = blockIdx.x;
  const int tid = threadIdx.x;
  if (bid < NB_GEMM) {
    const int mt = bid % 129;
    const int nt = (bid / 129) * 4 + (tid >> 6);   // 0..259
    const int l  = tid & 63;
    const int rc = l & 15;
    const int kg = (l >> 4) * 8;
    const _Float16* __restrict__ Ap =
        ((nt < 36) ? Hl : Hr) + (size_t)(mt * 16 + rc) * HDIM + kg;
    const _Float16* __restrict__ Bp = w2t + (size_t)(nt * 16 + rc) * HDIM + kg;
    f32x4 acc = {0.f, 0.f, 0.f, 0.f};
#pragma unroll
    for (int kc = 0; kc < 4; ++kc) {
      h8 a = *(const h8*)(Ap + kc * 32);
      h8 b = *(const h8*)(Bp + kc * 32);
      acc = __builtin_amdgcn_mfma_f32_16x16x32_f16(a, b, acc, 0, 0, 0);
    }
    const int n = nt * 16 + rc;
    const int q = l >> 4;
    const int g0 = mt * 16 + q * 4;
    const float vnf = __shfl(acc[0], (l + 16) & 63, 64);
    const __fp16 v0 = (__fp16)acc[0], v1 = (__fp16)acc[1];
    const __fp16 v2 = (__fp16)acc[2], v3 = (__fp16)acc[3];
    __fp16* rowp = ilut + 2 * n;
    if (g0 + 0 < GBIN) *(hp2*)(rowp + (size_t)(g0 + 0) * (2 * NC)) = mkh2(v0, v1);
    if (g0 + 1 < GBIN) *(hp2*)(rowp + (size_t)(g0 + 1) * (2 * NC)) = mkh2(v1, v2);
    if (g0 + 2 < GBIN) *(hp2*)(rowp + (size_t)(g0 + 2) * (2 * NC)) = mkh2(v2, v3);
    if (g0 + 3 < GBIN) {
      if (q < 3) *(hp2*)(rowp + (size_t)(g0 + 3) * (2 * NC)) = mkh2(v3, (__fp16)vnf);
      else        rowp[(size_t)(g0 + 3) * (2 * NC)] = v3;
    }
    if (q == 0 && g0 >= 1 && g0 <= GBIN)
      rowp[(size_t)(g0 - 1) * (2 * NC) + 1] = v0;
  } else {
    // ---- scan + bin-pair chunk emission ----
    __shared__ int lds[256];
    const int t = tid;
    int loc[8];
    int s = 0;
#pragma unroll
    for (int i = 0; i < 8; ++i) { loc[i] = cnt[t * 8 + i]; s += loc[i]; }
    lds[t] = s;
    __syncthreads();
    for (int o = 1; o < 256; o <<= 1) {
      int v = 0;
      if (t >= o) v = lds[t - o];
      __syncthreads();
      lds[t] += v;
      __syncthreads();
    }
    int run = lds[t] - s;
    int runs[8];
#pragma unroll
    for (int i = 0; i < 8; ++i) {
      runs[i] = run;
      offs[t * 8 + i] = run;
      woff[t * 8 + i] = run;
      run += loc[i];
    }
    if (t == 255) offs[GBIN] = run;

    // pair chunks: pair i covers bins (2i, 2i+1); thread owns pairs 4t..4t+3
    int ccnt[4];
    int csum = 0;
#pragma unroll
    for (int i = 0; i < 4; ++i) {
      ccnt[i] = (loc[2 * i] + loc[2 * i + 1] + 63) >> 6;
      csum += ccnt[i];
    }
    __syncthreads();
    lds[t] = csum;
    __syncthreads();
    for (int o = 1; o < 256; o <<= 1) {
      int v = 0;
      if (t >= o) v = lds[t - o];
      __syncthreads();
      lds[t] += v;
      __syncthreads();
    }
    int crun = lds[t] - csum;
#pragma unroll
    for (int i = 0; i < 4; ++i) {
      for (int c = 0; c < ccnt[i]; ++c) {
        chunk_pair[crun]  = t * 4 + i;
        chunk_start[crun] = runs[2 * i] + c * 64;
        ++crun;
      }
    }
    if (t == 255) nch[0] = lds[255];
  }
}

// ---------------- K3: counting-sort scatter ----------------
__global__ void k_scatter(const int* __restrict__ bin_e, int* __restrict__ woff,
                          int* __restrict__ sorted) {
  const int e = blockIdx.x * 256 + threadIdx.x;
  if (e >= NE) return;
  const int b = bin_e[e];
  if (b >= 0) {
    const int p = atomicAdd(&woff[b], 1);
    sorted[p] = e;
  }
}

// ---------------- K4: epilogue: 64-edge bin-pair chunk / 256 threads ----
// Stage ilut rows (2p, 2p+1) contiguously (33280 B LDS); each edge selects its
// row by bin parity. fdot2 compute body unchanged.
__global__ __launch_bounds__(256) void k_epi(
    const __fp16* __restrict__ ilut, const int* __restrict__ chunk_pair,
    const int* __restrict__ chunk_start, const int* __restrict__ offs,
    const int* __restrict__ sorted, const float* __restrict__ f_e,
    const int* __restrict__ bin_e, const int* __restrict__ ei,
    const float* __restrict__ pos, const float* __restrict__ x,
    float* __restrict__ out, const int* __restrict__ nch) {
  __shared__ __fp16 WPbuf[4 * NC];     // 2 ilut rows = 33280 B
  const int bid = blockIdx.x;
  if (bid >= nch[0]) return;
  const int base  = chunk_pair[bid] * 2;          // first bin of the pair
  const int start = chunk_start[bid];
  const int end0  = offs[base + 2];
  const int end   = (start + 64 < end0) ? (start + 64) : end0;
  const int tid = threadIdx.x;
  {  // stage: linear copy of 2 contiguous pre-interleaved rows (2080 x uint4)
    const uint4* src = (const uint4*)(ilut + (size_t)base * (2 * NC));
    uint4* dst = (uint4*)WPbuf;
    for (int i = tid; i < 2080; i += 256) dst[i] = src[i];
  }
  __syncthreads();
  const int s  = tid & 3;
  const int qb = (tid & 63) & ~3;
  const int slot = start + (tid >> 2);
  if (slot >= end) return;

  const int e = sorted[slot];
  const __fp16* __restrict__ WP = WPbuf + (size_t)(bin_e[e] - base) * (2 * NC);
  const float f = f_e[e];
  const float fm = 1.f - f;
  const int rec = ei[e], lig = ei[NE + e];
  const float ax = pos[lig * 3 + 0] - pos[rec * 3 + 0];
  const float ay = pos[lig * 3 + 1] - pos[rec * 3 + 1];
  const float az = pos[lig * 3 + 2] - pos[rec * 3 + 2];
  const float d = sqrtf(ax * ax + ay * ay + az * az);
  const float inv = SQ3C / fmaxf(d, 1e-12f);
  const float sh0 = ax * inv, sh1 = ay * inv, sh2 = az * inv;

  // ---- lig features ----
  float s1[16], v1[24];
  {
    const float4* xl = (const float4*)(x + (size_t)lig * 40);
#pragma unroll
    for (int j = 0; j < 4; ++j) {
      float4 v = xl[j];
      s1[j * 4 + 0] = v.x; s1[j * 4 + 1] = v.y; s1[j * 4 + 2] = v.z; s1[j * 4 + 3] = v.w;
    }
#pragma unroll
    for (int j = 0; j < 6; ++j) {
      float4 v = xl[4 + j];
      v1[j * 4 + 0] = v.x; v1[j * 4 + 1] = v.y; v1[j * 4 + 2] = v.z; v1[j * 4 + 3] = v.w;
    }
  }
  float vs[8];
#pragma unroll
  for (int u = 0; u < 8; ++u)
    vs[u] = (v1[u * 3] * sh0 + v1[u * 3 + 1] * sh1 + v1[u * 3 + 2] * sh2) * INV_SQ3;

  // ---- layer 1: sa (lane owns w = 4s..4s+3); lerp folded in fdot2 ----
  float A[4] = {0.f, 0.f, 0.f, 0.f};
#pragma unroll
  for (int u = 0; u < 16; ++u) {   // W000 @ 0
    hp8 w = *(const hp8*)(WP + 2 * (u * 16 + s * 4));
    hp2 sp = pk2(s1[u] * fm, s1[u] * f);
    A[0] = fdot2f(mkh2(w[0], w[1]), sp, A[0]);
    A[1] = fdot2f(mkh2(w[2], w[3]), sp, A[1]);
    A[2] = fdot2f(mkh2(w[4], w[5]), sp, A[2]);
    A[3] = fdot2f(mkh2(w[6], w[7]), sp, A[3]);
  }
#pragma unroll
  for (int u = 0; u < 8; ++u) {    // W110 @ 448
    hp8 w = *(const hp8*)(WP + 2 * (448 + u * 16 + s * 4));
    hp2 sp = pk2(vs[u] * fm, vs[u] * f);
    A[0] = fdot2f(mkh2(w[0], w[1]), sp, A[0]);
    A[1] = fdot2f(mkh2(w[2], w[3]), sp, A[1]);
    A[2] = fdot2f(mkh2(w[4], w[5]), sp, A[2]);
    A[3] = fdot2f(mkh2(w[6], w[7]), sp, A[3]);
  }
  const float sa0 = C0_1F * A[0];
  const float sa1 = C0_1F * A[1];
  const float sa2 = C0_1F * A[2];
  const float sa3 = C0_1F * A[3];

  // ---- layer 1: va (lane owns w = 2s, 2s+1) ----
  float vaA0, vaA1, vaA2, vaB0, vaB1, vaB2;
  {
    float cA = 0.f, cB = 0.f;
#pragma unroll
    for (int u = 0; u < 16; ++u) {  // W011 @ 256
      hp4 w = *(const hp4*)(WP + 2 * (256 + u * 8 + s * 2));
      hp2 sp = pk2(s1[u] * fm, s1[u] * f);
      cA = fdot2f(mkh2(w[0], w[1]), sp, cA);
      cB = fdot2f(mkh2(w[2], w[3]), sp, cB);
    }
    float tAx = 0.f, tAy = 0.f, tAz = 0.f, tBx = 0.f, tBy = 0.f, tBz = 0.f;
#pragma unroll
    for (int u = 0; u < 8; ++u) {   // W101 @ 384
      hp4 w = *(const hp4*)(WP + 2 * (384 + u * 8 + s * 2));
      hp2 px = pk2(v1[u * 3] * fm,     v1[u * 3] * f);
      hp2 py = pk2(v1[u * 3 + 1] * fm, v1[u * 3 + 1] * f);
      hp2 pz = pk2(v1[u * 3 + 2] * fm, v1[u * 3 + 2] * f);
      hp2 pa = mkh2(w[0], w[1]);
      hp2 pb = mkh2(w[2], w[3]);
      tAx = fdot2f(pa, px, tAx); tAy = fdot2f(pa, py, tAy); tAz = fdot2f(pa, pz, tAz);
      tBx = fdot2f(pb, px, tBx); tBy = fdot2f(pb, py, tBy); tBz = fdot2f(pb, pz, tBz);
    }
    vaA0 = C1_1_OS3F * (cA * sh0 + tAx);
    vaA1 = C1_1_OS3F * (cA * sh1 + tAy);
    vaA2 = C1_1_OS3F * (cA * sh2 + tAz);
    vaB0 = C1_1_OS3F * (cB * sh0 + tBx);
    vaB1 = C1_1_OS3F * (cB * sh1 + tBy);
    vaB2 = C1_1_OS3F * (cB * sh2 + tBz);
  }

  // ---- quad allgather (within wave) ----
  float saF[16];
#pragma unroll
  for (int k = 0; k < 16; ++k) {
    const float v = ((k & 3) == 0) ? sa0 : ((k & 3) == 1) ? sa1 : ((k & 3) == 2) ? sa2 : sa3;
    saF[k] = __shfl(v, qb + (k >> 2), 64);
  }
  float vaF[24];
#pragma unroll
  for (int w = 0; w < 8; ++w) {
    const int src = qb + (w >> 1);
    const float x0 = (w & 1) ? vaB0 : vaA0;
    const float x1 = (w & 1) ? vaB1 : vaA1;
    const float x2 = (w & 1) ? vaB2 : vaA2;
    vaF[w * 3 + 0] = __shfl(x0, src, 64);
    vaF[w * 3 + 1] = __shfl(x1, src, 64);
    vaF[w * 3 + 2] = __shfl(x2, src, 64);
  }

  // ---- rec features: lane's v-subset ----
  const float* xr = x + (size_t)rec * 40;
  const float sbl0 = xr[s],      sbl1 = xr[4 + s];
  const float sbl2 = xr[8 + s],  sbl3 = xr[12 + s];
  const float vbA0 = xr[16 + s * 3 + 0], vbA1 = xr[16 + s * 3 + 1], vbA2 = xr[16 + s * 3 + 2];
  const float vbB0 = xr[16 + (s + 4) * 3 + 0], vbB1 = xr[16 + (s + 4) * 3 + 1], vbB2 = xr[16 + (s + 4) * 3 + 2];

  float oe[20];

  // ===== layer 2: s_out =====
  {
    float so[8];
#pragma unroll
    for (int w = 0; w < 8; ++w) so[w] = 0.f;
#pragma unroll
    for (int u = 0; u < 16; ++u) {   // W000 @ 576: [u:16][v:16][w:8], v = vv*4+s
      const float su = saF[u];
      const __fp16* rp = WP + 2 * (576 + u * 128 + s * 8);
#pragma unroll
      for (int vv = 0; vv < 4; ++vv) {
        const float q = su * ((vv == 0) ? sbl0 : (vv == 1) ? sbl1 : (vv == 2) ? sbl2 : sbl3);
        hp2 qp = pk2(q * fm, q * f);
        hp8 wa = *(const hp8*)(rp + 2 * (vv * 32));
        hp8 wb = *(const hp8*)(rp + 2 * (vv * 32) + 8);
        so[0] = fdot2f(mkh2(wa[0], wa[1]), qp, so[0]);
        so[1] = fdot2f(mkh2(wa[2], wa[3]), qp, so[1]);
        so[2] = fdot2f(mkh2(wa[4], wa[5]), qp, so[2]);
        so[3] = fdot2f(mkh2(wa[6], wa[7]), qp, so[3]);
        so[4] = fdot2f(mkh2(wb[0], wb[1]), qp, so[4]);
        so[5] = fdot2f(mkh2(wb[2], wb[3]), qp, so[5]);
        so[6] = fdot2f(mkh2(wb[4], wb[5]), qp, so[6]);
        so[7] = fdot2f(mkh2(wb[6], wb[7]), qp, so[7]);
      }
    }
#pragma unroll
    for (int u = 0; u < 8; ++u) {    // W110 @ 3648: [u:8][v:8][w:8], v = vv*4+s
      const float a0 = vaF[u * 3], a1 = vaF[u * 3 + 1], a2 = vaF[u * 3 + 2];
      const __fp16* rp = WP + 2 * (3648 + u * 64 + s * 8);
#pragma unroll
      for (int vv = 0; vv < 2; ++vv) {
        const float b0v = vv ? vbB0 : vbA0;
        const float b1v = vv ? vbB1 : vbA1;
        const float b2v = vv ? vbB2 : vbA2;
        const float dd = (a0 * b0v + a1 * b1v + a2 * b2v) * INV_SQ3;
        hp2 qp = pk2(dd * fm, dd * f);
        hp8 wa = *(const hp8*)(rp + 2 * (vv * 32));
        hp8 wb = *(const hp8*)(rp + 2 * (vv * 32) + 8);
        so[0] = fdot2f(mkh2(wa[0], wa[1]), qp, so[0]);
        so[1] = fdot2f(mkh2(wa[2], wa[3]), qp, so[1]);
        so[2] = fdot2f(mkh2(wa[4], wa[5]), qp, so[2]);
        so[3] = fdot2f(mkh2(wa[6], wa[7]), qp, so[3]);
        so[4] = fdot2f(mkh2(wb[0], wb[1]), qp, so[4]);
        so[5] = fdot2f(mkh2(wb[2], wb[3]), qp, so[5]);
        so[6] = fdot2f(mkh2(wb[4], wb[5]), qp, so[6]);
        so[7] = fdot2f(mkh2(wb[6], wb[7]), qp, so[7]);
      }
    }
#pragma unroll
    for (int w = 0; w < 8; ++w) oe[w] = C0_2F * so[w];
  }

  // ===== layer 2: v_out =====
  {
    float uo[12];
#pragma unroll
    for (int w = 0; w < 12; ++w) uo[w] = 0.f;
#pragma unroll
    for (int u = 0; u < 16; ++u) {   // W011 @ 2624: [u:16][v:8][w:4], v = vv*4+s
      const float su = saF[u];
      const __fp16* rp = WP + 2 * (2624 + u * 32 + s * 4);
#pragma unroll
      for (int vv = 0; vv < 2; ++vv) {
        const float q0 = su * (vv ? vbB0 : vbA0);
        const float q1 = su * (vv ? vbB1 : vbA1);
        const float q2 = su * (vv ? vbB2 : vbA2);
        hp2 q0p = pk2(q0 * fm, q0 * f);
        hp2 q1p = pk2(q1 * fm, q1 * f);
        hp2 q2p = pk2(q2 * fm, q2 * f);
        hp8 w = *(const hp8*)(rp + 2 * (vv * 16));
        hp2 p0 = mkh2(w[0], w[1]);
        hp2 p1 = mkh2(w[2], w[3]);
        hp2 p2 = mkh2(w[4], w[5]);
        hp2 p3 = mkh2(w[6], w[7]);
        uo[0] = fdot2f(p0, q0p, uo[0]); uo[1]  = fdot2f(p0, q1p, uo[1]);  uo[2]  = fdot2f(p0, q2p, uo[2]);
        uo[3] = fdot2f(p1, q0p, uo[3]); uo[4]  = fdot2f(p1, q1p, uo[4]);  uo[5]  = fdot2f(p1, q2p, uo[5]);
        uo[6] = fdot2f(p2, q0p, uo[6]); uo[7]  = fdot2f(p2, q1p, uo[7]);  uo[8]  = fdot2f(p2, q2p, uo[8]);
        uo[9] = fdot2f(p3, q0p, uo[9]); uo[10] = fdot2f(p3, q1p, uo[10]); uo[11] = fdot2f(p3, q2p, uo[11]);
      }
    }
#pragma unroll
    for (int u = 0; u < 8; ++u) {    // W101 @ 3136: [u:8][v:16][w:4], v = vv*4+s
      const float a0 = vaF[u * 3], a1 = vaF[u * 3 + 1], a2 = vaF[u * 3 + 2];
      const __fp16* rp = WP + 2 * (3136 + u * 64 + s * 4);
#pragma unroll
      for (int vv = 0; vv < 4; ++vv) {
        const float sbv = (vv == 0) ? sbl0 : (vv == 1) ? sbl1 : (vv == 2) ? sbl2 : sbl3;
        const float q0 = a0 * sbv, q1 = a1 * sbv, q2 = a2 * sbv;
        hp2 q0p = pk2(q0 * fm, q0 * f);
        hp2 q1p = pk2(q1 * fm, q1 * f);
        hp2 q2p = pk2(q2 * fm, q2 * f);
        hp8 w = *(const hp8*)(rp + 2 * (vv * 16));
        hp2 p0 = mkh2(w[0], w[1]);
        hp2 p1 = mkh2(w[2], w[3]);
        hp2 p2 = mkh2(w[4], w[5]);
        hp2 p3 = mkh2(w[6], w[7]);
        uo[0] = fdot2f(p0, q0p, uo[0]); uo[1]  = fdot2f(p0, q1p, uo[1]);  uo[2]  = fdot2f(p0, q2p, uo[2]);
        uo[3] = fdot2f(p1, q0p, uo[3]); uo[4]  = fdot2f(p1, q1p, uo[4]);  uo[5]  = fdot2f(p1, q2p, uo[5]);
        uo[6] = fdot2f(p2, q0p, uo[6]); uo[7]  = fdot2f(p2, q1p, uo[7]);  uo[8]  = fdot2f(p2, q2p, uo[8]);
        uo[9] = fdot2f(p3, q0p, uo[9]); uo[10] = fdot2f(p3, q1p, uo[10]); uo[11] = fdot2f(p3, q2p, uo[11]);
      }
    }
#pragma unroll
    for (int w = 0; w < 12; ++w) oe[8 + w] = C1_2_OS3F * uo[w];
  }

  // ---- quad butterfly reduce + store ----
#pragma unroll
  for (int w = 0; w < 20; ++w) {
    oe[w] += __shfl_xor(oe[w], 1, 64);
    oe[w] += __shfl_xor(oe[w], 2, 64);
  }
  if (s == 0) {
    float4* op = (float4*)(out + (size_t)e * 20);
#pragma unroll
    for (int j = 0; j < 5; ++j) {
      float4 o4;
      o4.x = oe[j * 4 + 0]; o4.y = oe[j * 4 + 1];
      o4.z = oe[j * 4 + 2]; o4.w = oe[j * 4 + 3];
      op[j] = o4;
    }
  }
}

// ---------------- host ----------------
extern "C" void kernel_launch(void* const* d_in, const int* in_sizes, int n_in,
                              void* d_out, int out_size, void* d_ws, size_t ws_size,
                              hipStream_t stream) {
  const int*   ei  = (const int*)d_in[0];
  const float* pos = (const float*)d_in[1];
  const float* x   = (const float*)d_in[2];
  const float* lw1 = (const float*)d_in[3];
  const float* lw2 = (const float*)d_in[4];
  const float* rw1 = (const float*)d_in[5];
  const float* rw2 = (const float*)d_in[6];
  float* out = (float*)d_out;
  char*  ws  = (char*)d_ws;

  size_t o = 0;
  __fp16* ilut = (__fp16*)(ws + o); o += (size_t)GBIN * (2 * NC) * 2;
  o = (o + 15) & ~(size_t)15;
  _Float16* Hl  = (_Float16*)(ws + o); o += (size_t)MPAD * HDIM * 2;
  _Float16* Hr  = (_Float16*)(ws + o); o += (size_t)MPAD * HDIM * 2;
  _Float16* w2t = (_Float16*)(ws + o); o += (size_t)NC * HDIM * 2;
  o = (o + 15) & ~(size_t)15;
  int*   bin_e = (int*)(ws + o);  o += (size_t)NE * 4;
  float* f_e   = (float*)(ws + o); o += (size_t)NE * 4;
  int*   cnt   = (int*)(ws + o);  o += (size_t)GBIN * 4;
  int*   offs  = (int*)(ws + o);  o += (size_t)(GBIN + 1) * 4 + 12;
  int*   woff  = (int*)(ws + o);  o += (size_t)GBIN * 4;
  int*   sorted = (int*)(ws + o); o += (size_t)NE * 4;
  int*   chunk_pair  = (int*)(ws + o); o += (size_t)NCHMAX * 4;
  int*   chunk_start = (int*)(ws + o); o += (size_t)NCHMAX * 4;
  int*   nch = (int*)(ws + o); o += 16;

  // ACT_C on host (runs at capture time, not in the timed graph)
  double ssum = 0.0;
  const double dz = 20.0 / 40000.0;
  for (int i = 0; i <= 40000; ++i) {
    const double z = -10.0 + dz * (double)i;
    const double sil = z / (1.0 + exp(-z));
    const double phi = exp(-0.5 * z * z) / sqrt(2.0 * M_PI);
    ssum += sil * sil * phi;
  }
  const float actc = (float)(1.0 / sqrt(ssum * dz));
  const float k0c  = (float)(1.14136 * exp(2.0));

  hipMemsetAsync(cnt, 0, GBIN * 4, stream);
  k_fused<<<MPAD + NB_W2T + NB_EDGE, 256, 0, stream>>>(
      lw1, rw1, lw2, rw2, actc, k0c, Hl, Hr, w2t, ei, pos, out, bin_e, f_e, cnt);
  k_lutm<<<NB_GEMM + 1, 256, 0, stream>>>(Hl, Hr, w2t, ilut, cnt, offs, woff,
                                          chunk_pair, chunk_start, nch);
  k_scatter<<<(NE + 255) / 256, 256, 0, stream>>>(bin_e, woff, sorted);
  k_epi<<<NCHMAX, 256, 0, stream>>>(ilut, chunk_pair, chunk_start, offs, sorted, f_e,
                                    bin_e, ei, pos, x, out, nch);
}